// Round 1
// baseline (2373.551 us; speedup 1.0000x reference)
//
#include <hip/hip_runtime.h>
#include <stdint.h>

#define LL long long

// ======================================================================
// Generic 3x3 SAME conv (cross-correlation), stride 1.
// tile = 8 rows x 32 cols (256 positions = 256 threads, 1 pos/thread),
// 32 output channels per block held in registers, IC chunked by 4 via LDS.
// Weights are read with wave-uniform indices -> compiler emits s_load.
// Output is accumulated with atomicAdd (outputs pre-zeroed) so IC can be
// split across blocks for occupancy.
// out[b*OCtot*HW + oc*ocs + pos*ps]
// ======================================================================
__global__ __launch_bounds__(256) void conv3x3(
    const float* __restrict__ in, const float* __restrict__ w, float* __restrict__ out,
    int H, int W, int ICt, int ic_per, int ic_splits, int OCtot, int tiles_x,
    LL ocs, LL ps)
{
  __shared__ __align__(16) float xs[4][10][34];
  const int t    = threadIdx.x;
  const int tile = blockIdx.x;
  const int oc0  = blockIdx.y * 32;
  const int z    = blockIdx.z;
  const int b    = z / ic_splits;
  const int ic0  = (z - b * ic_splits) * ic_per;
  const int HW   = H * W;
  const int ty0  = (tile / tiles_x) * 8;
  const int tx0  = (tile % tiles_x) * 32;
  const int ty   = t >> 5, tx = t & 31;

  const float* inb = in + (LL)b * ICt * HW;

  float acc[32];
#pragma unroll
  for (int i = 0; i < 32; ++i) acc[i] = 0.f;

  for (int ic = ic0; ic < ic0 + ic_per; ic += 4) {
    __syncthreads();
    for (int idx = t; idx < 1360; idx += 256) {
      int icl = idx / 340; int rem = idx - icl * 340;
      int ry  = rem / 34;  int rx  = rem - ry * 34;
      int gy  = ty0 + ry - 1, gx = tx0 + rx - 1;
      float v = 0.f;
      if ((unsigned)gy < (unsigned)H && (unsigned)gx < (unsigned)W)
        v = inb[(LL)(ic + icl) * HW + gy * W + gx];
      xs[icl][ry][rx] = v;
    }
    __syncthreads();
#pragma unroll
    for (int icl = 0; icl < 4; ++icl) {
      float xv[9];
#pragma unroll
      for (int dy = 0; dy < 3; ++dy)
#pragma unroll
        for (int dx = 0; dx < 3; ++dx)
          xv[dy * 3 + dx] = xs[icl][ty + dy][tx + dx];
      const float* wic = w + ((LL)oc0 * ICt + (ic + icl)) * 9;
#pragma unroll
      for (int oc = 0; oc < 32; ++oc) {
        const float* wo = wic + (LL)oc * ICt * 9;  // wave-uniform -> s_load
        float s = acc[oc];
        s = fmaf(xv[0], wo[0], s);
        s = fmaf(xv[1], wo[1], s);
        s = fmaf(xv[2], wo[2], s);
        s = fmaf(xv[3], wo[3], s);
        s = fmaf(xv[4], wo[4], s);
        s = fmaf(xv[5], wo[5], s);
        s = fmaf(xv[6], wo[6], s);
        s = fmaf(xv[7], wo[7], s);
        s = fmaf(xv[8], wo[8], s);
        acc[oc] = s;
      }
    }
  }
  const LL ob = (LL)b * OCtot * HW + (LL)((ty0 + ty) * W + tx0 + tx) * ps;
#pragma unroll
  for (int oc = 0; oc < 32; ++oc)
    atomicAdd(&out[ob + (LL)(oc0 + oc) * ocs], acc[oc]);
}

// ======================================================================
// cf[b][n] = sum_c x1[b][c][n] * wc[c]   (1x1 conv, 256-dot per pixel)
// grid (16,8), 256 threads; lanes cover consecutive n -> coalesced.
// ======================================================================
__global__ __launch_bounds__(256) void cf_dot(
    const float* __restrict__ x1, const float* __restrict__ wc, float* __restrict__ cf)
{
  const int b = blockIdx.y;
  const int n = blockIdx.x * 256 + threadIdx.x;
  const float* xp = x1 + (LL)b * 256 * 4096 + n;
  float a = 0.f;
#pragma unroll 4
  for (int c = 0; c < 256; ++c)
    a = fmaf(xp[(LL)c * 4096], wc[c], a);
  cf[b * 4096 + n] = a;
}

// ======================================================================
// softmax over 4096 per batch: cfs = softmax(cf). grid 8 x 1024 threads.
// ======================================================================
__global__ __launch_bounds__(1024) void cf_softmax(
    const float* __restrict__ cf, float* __restrict__ cfs)
{
  const int b = blockIdx.x, t = threadIdx.x;
  __shared__ float r1[16];
  __shared__ float r2[16];
  float v[4];
#pragma unroll
  for (int j = 0; j < 4; ++j) v[j] = cf[b * 4096 + t + 1024 * j];
  float mx = fmaxf(fmaxf(v[0], v[1]), fmaxf(v[2], v[3]));
#pragma unroll
  for (int k = 1; k <= 32; k <<= 1) mx = fmaxf(mx, __shfl_xor(mx, k));
  const int wv = t >> 6;
  if ((t & 63) == 0) r1[wv] = mx;
  __syncthreads();
  float m2 = r1[0];
#pragma unroll
  for (int i = 1; i < 16; ++i) m2 = fmaxf(m2, r1[i]);
  float e[4]; float s = 0.f;
#pragma unroll
  for (int j = 0; j < 4; ++j) { e[j] = __expf(v[j] - m2); s += e[j]; }
#pragma unroll
  for (int k = 1; k <= 32; k <<= 1) s += __shfl_xor(s, k);
  if ((t & 63) == 0) r2[wv] = s;
  __syncthreads();
  float s2 = 0.f;
#pragma unroll
  for (int i = 0; i < 16; ++i) s2 += r2[i];
  const float inv = 1.f / s2;
#pragma unroll
  for (int j = 0; j < 4; ++j) cfs[b * 4096 + t + 1024 * j] = e[j] * inv;
}

// ======================================================================
// T[b][c][dy*3+dx] = sum_{y,x} x1[b][c][y][x] * cfs[b][y+1-dy][x+1-dx]
// (valid indices only). This algebraically replaces the big wch conv:
// pool[b][c] = sum_{c',k} wch[c][c'][k] * T[b][c'][k].
// grid (16 chunks of 4 rows, 8 b), 256 threads, atomicAdd into T (zeroed).
// ======================================================================
__global__ __launch_bounds__(256) void ykern(
    const float* __restrict__ x1, const float* __restrict__ cfs, float* __restrict__ T)
{
  __shared__ float cl[6][64];
  const int chunk = blockIdx.x, b = blockIdx.y, t = threadIdx.x;
  for (int idx = t; idx < 384; idx += 256) {
    int lr = idx >> 6, col = idx & 63;
    int gr = chunk * 4 - 1 + lr;
    cl[lr][col] = ((unsigned)gr < 64u) ? cfs[b * 4096 + gr * 64 + col] : 0.f;
  }
  __syncthreads();
  const int c = t;
  float a[9];
#pragma unroll
  for (int k = 0; k < 9; ++k) a[k] = 0.f;
  const float* xp = x1 + ((LL)b * 256 + c) * 4096 + chunk * 256;
  for (int i = 0; i < 256; ++i) {
    float xv = xp[i];
    int yl = i >> 6, col = i & 63;
#pragma unroll
    for (int dy = 0; dy < 3; ++dy) {
      int lr = yl + 2 - dy;  // LDS row for global row y'+1-dy
#pragma unroll
      for (int dx = 0; dx < 3; ++dx) {
        int cc = col + 1 - dx;
        float f = ((unsigned)cc < 64u) ? cl[lr][cc] : 0.f;
        a[dy * 3 + dx] = fmaf(xv, f, a[dy * 3 + dx]);
      }
    }
  }
#pragma unroll
  for (int k = 0; k < 9; ++k)
    atomicAdd(&T[((LL)b * 256 + c) * 9 + k], a[k]);
}

// ======================================================================
// pool = wch . T ; t1 = wt1.pool + bt1 ; LayerNorm(32) ; relu ;
// cwp1[b][c] = 1 + (wt2.t + bt2)[c].   grid 8 x 256 threads.
// ======================================================================
__global__ __launch_bounds__(256) void chw(
    const float* __restrict__ T, const float* __restrict__ wch,
    const float* __restrict__ wt1, const float* __restrict__ bt1,
    const float* __restrict__ lng, const float* __restrict__ lnb,
    const float* __restrict__ wt2, const float* __restrict__ bt2,
    float* __restrict__ cwp1)
{
  const int b = blockIdx.x, t = threadIdx.x;
  __shared__ __align__(16) float Tl[2304];
  __shared__ float pool[256];
  __shared__ float tt[32];
  for (int idx = t; idx < 2304; idx += 256) Tl[idx] = T[(LL)b * 2304 + idx];
  __syncthreads();
  {
    const float4* wp = (const float4*)(wch + (LL)t * 2304);
    const float4* tp = (const float4*)Tl;
    float a = 0.f;
    for (int i = 0; i < 576; ++i) {
      float4 w4 = wp[i], t4 = tp[i];
      a = fmaf(w4.x, t4.x, a); a = fmaf(w4.y, t4.y, a);
      a = fmaf(w4.z, t4.z, a); a = fmaf(w4.w, t4.w, a);
    }
    pool[t] = a;
  }
  __syncthreads();
  if (t < 64) {
    float tv = 0.f;
    if (t < 32) {
      const float* wp = wt1 + (LL)t * 256;
      for (int c = 0; c < 256; ++c) tv = fmaf(wp[c], pool[c], tv);
      tv += bt1[t];
    }
    // LN over 32 lanes (masks <=16 stay within 32-lane half)
    float s = tv;
#pragma unroll
    for (int k = 1; k <= 16; k <<= 1) s += __shfl_xor(s, k);
    float mu = s * (1.f / 32.f);
    float d = tv - mu;
    float vs = d * d;
#pragma unroll
    for (int k = 1; k <= 16; k <<= 1) vs += __shfl_xor(vs, k);
    float var = vs * (1.f / 32.f);
    if (t < 32) {
      float nrm = d / sqrtf(var + 1e-5f);
      float y = nrm * lng[t] + lnb[t];
      tt[t] = fmaxf(y, 0.f);
    }
  }
  __syncthreads();
  {
    float s2 = bt2[t];
    const float* wp = wt2 + (LL)t * 32;
#pragma unroll
    for (int i = 0; i < 32; ++i) s2 = fmaf(wp[i], tt[i], s2);
    cwp1[b * 256 + t] = 1.f + s2;
  }
}

// ======================================================================
// Fused attention + epilogue.  One block = batch b, 8 query columns.
// q   [B][32][4096]   (natural)
// kt  [B][1024][32]   (transposed by conv: ocs=1, ps=32)
// vt  [B][1024][256]  (transposed by conv: ocs=1, ps=256)
// phase 1: S[n][m] = sum_c K[c][n] q[c][m]          (fp32, LDS 32KB)
// phase 2: softmax over n per m -> P bf16 (unnormalized e), invl[m]
// phase 3: att[c][m] = sum_n V[c][n] P[n][m]; V from global (L2-hot),
//          8c x 8m register tile per thread, 8-way n-split + butterfly.
// epilogue: out = att*invl + x1*(1+cw)
// ======================================================================
__device__ __forceinline__ unsigned short f2bf(float f) {
  unsigned u = __float_as_uint(f);
  unsigned r = (u + 0x7fffu + ((u >> 16) & 1u)) >> 16;
  return (unsigned short)r;
}

__global__ __launch_bounds__(256) void attn(
    const float* __restrict__ q, const float* __restrict__ kt,
    const float* __restrict__ vt, const float* __restrict__ x1,
    const float* __restrict__ cwp1, float* __restrict__ out)
{
  __shared__ __align__(16) float S[1024][8];
  __shared__ __align__(16) unsigned short P[1024][8];
  __shared__ __align__(16) float qld[32][8];
  __shared__ float red[2][4][8];
  __shared__ float invl[8];

  const int t = threadIdx.x;
  const int b = blockIdx.y;
  const int mb = blockIdx.x * 8;

  // stage q tile
  {
    int c = t >> 3, m = t & 7;
    qld[c][m] = q[((LL)b * 32 + c) * 4096 + mb + m];
  }
  __syncthreads();

  // ---- phase 1: logits ----
#pragma unroll
  for (int jp = 0; jp < 2; ++jp) {
    const int n0 = t + 512 * jp;
    const int n1 = n0 + 256;
    float K0[32], K1[32];
    const float4* kp0 = (const float4*)(kt + ((LL)b * 1024 + n0) * 32);
    const float4* kp1 = (const float4*)(kt + ((LL)b * 1024 + n1) * 32);
#pragma unroll
    for (int r = 0; r < 8; ++r) {
      float4 a = kp0[r];
      K0[4 * r] = a.x; K0[4 * r + 1] = a.y; K0[4 * r + 2] = a.z; K0[4 * r + 3] = a.w;
      float4 c4 = kp1[r];
      K1[4 * r] = c4.x; K1[4 * r + 1] = c4.y; K1[4 * r + 2] = c4.z; K1[4 * r + 3] = c4.w;
    }
    float a0[8], a1[8];
#pragma unroll
    for (int m = 0; m < 8; ++m) { a0[m] = 0.f; a1[m] = 0.f; }
#pragma unroll
    for (int c = 0; c < 32; ++c) {
      float4 qa = *(const float4*)&qld[c][0];
      float4 qb = *(const float4*)&qld[c][4];
      float qv[8] = {qa.x, qa.y, qa.z, qa.w, qb.x, qb.y, qb.z, qb.w};
      float k0 = K0[c], k1 = K1[c];
#pragma unroll
      for (int m = 0; m < 8; ++m) {
        a0[m] = fmaf(k0, qv[m], a0[m]);
        a1[m] = fmaf(k1, qv[m], a1[m]);
      }
    }
#pragma unroll
    for (int m = 0; m < 8; ++m) { S[n0][m] = a0[m]; S[n1][m] = a1[m]; }
  }
  __syncthreads();

  // ---- phase 2: softmax over n ----
  {
    const int m = t & 7, l = t >> 3;  // conflict-free column scan
    float mx = -3.4e38f;
    for (int i = 0; i < 32; ++i) mx = fmaxf(mx, S[l + 32 * i][m]);
    mx = fmaxf(mx, __shfl_xor(mx, 8));
    mx = fmaxf(mx, __shfl_xor(mx, 16));
    mx = fmaxf(mx, __shfl_xor(mx, 32));
    const int wv = t >> 6;
    if ((t & 63) < 8) red[0][wv][m] = mx;
    __syncthreads();
    mx = fmaxf(fmaxf(red[0][0][m], red[0][1][m]), fmaxf(red[0][2][m], red[0][3][m]));
    float sm = 0.f;
    for (int i = 0; i < 32; ++i) {
      int n = l + 32 * i;
      float e = __expf(S[n][m] - mx);
      sm += e;
      P[n][m] = f2bf(e);
    }
    sm += __shfl_xor(sm, 8);
    sm += __shfl_xor(sm, 16);
    sm += __shfl_xor(sm, 32);
    if ((t & 63) < 8) red[1][wv][m] = sm;
    __syncthreads();
    sm = red[1][0][m] + red[1][1][m] + red[1][2][m] + red[1][3][m];
    if (t < 8) invl[t] = 1.f / sm;  // t<8 <=> l==0, m==t
  }
  __syncthreads();

  // ---- phase 3: att = V @ P ----
  const int ng = t & 7, cb = t >> 3;
  const int c0 = cb * 8;
  float acc[8][8];
#pragma unroll
  for (int cl = 0; cl < 8; ++cl)
#pragma unroll
    for (int m = 0; m < 8; ++m) acc[cl][m] = 0.f;

  const float* vbase = vt + (LL)b * 1024 * 256 + (LL)ng * 256 + c0;
  const unsigned short* Pbase = &P[ng][0];
#pragma unroll 2
  for (int i = 0; i < 128; ++i) {
    const float4* vp = (const float4*)(vbase + (LL)i * 2048);
    float4 v0 = vp[0], v1 = vp[1];
    uint4 pr = *(const uint4*)(Pbase + (size_t)i * 64);
    float p[8];
    p[0] = __uint_as_float(pr.x << 16); p[1] = __uint_as_float(pr.x & 0xffff0000u);
    p[2] = __uint_as_float(pr.y << 16); p[3] = __uint_as_float(pr.y & 0xffff0000u);
    p[4] = __uint_as_float(pr.z << 16); p[5] = __uint_as_float(pr.z & 0xffff0000u);
    p[6] = __uint_as_float(pr.w << 16); p[7] = __uint_as_float(pr.w & 0xffff0000u);
    float vv[8] = {v0.x, v0.y, v0.z, v0.w, v1.x, v1.y, v1.z, v1.w};
#pragma unroll
    for (int cl = 0; cl < 8; ++cl)
#pragma unroll
      for (int m = 0; m < 8; ++m)
        acc[cl][m] = fmaf(vv[cl], p[m], acc[cl][m]);
  }

  // butterfly reduce over ng (keep-half): ends with acc[0][*] = row c0+ng
#pragma unroll
  for (int bm = 4; bm >= 1; bm >>= 1) {
    const bool up = (ng & bm) != 0;
#pragma unroll
    for (int j = 0; j < 8; ++j) {
      if (j >= bm) break;
#pragma unroll
      for (int m = 0; m < 8; ++m) {
        float send = up ? acc[j][m] : acc[j + bm][m];
        float keep = up ? acc[j + bm][m] : acc[j][m];
        float got = __shfl_xor(send, bm);
        acc[j][m] = keep + got;
      }
    }
  }

  // ---- epilogue ----
  {
    const int c = c0 + ng;
    const float cw = cwp1[b * 256 + c];
    const float* x1p = x1 + ((LL)b * 256 + c) * 4096 + mb;
    float* op = out + ((LL)b * 256 + c) * 4096 + mb;
#pragma unroll
    for (int m = 0; m < 8; ++m)
      op[m] = fmaf(acc[0][m], invl[m], x1p[m] * cw);
  }
}

// ======================================================================
// launch
// ======================================================================
extern "C" void kernel_launch(void* const* d_in, const int* in_sizes, int n_in,
                              void* d_out, int out_size, void* d_ws, size_t ws_size,
                              hipStream_t stream) {
  const float* x1  = (const float*)d_in[0];
  const float* x2  = (const float*)d_in[1];
  const float* wq  = (const float*)d_in[2];
  const float* wk  = (const float*)d_in[3];
  const float* wv  = (const float*)d_in[4];
  const float* wc  = (const float*)d_in[5];
  const float* wch = (const float*)d_in[6];
  const float* wt1 = (const float*)d_in[7];
  const float* bt1 = (const float*)d_in[8];
  const float* lng = (const float*)d_in[9];
  const float* lnb = (const float*)d_in[10];
  const float* wt2 = (const float*)d_in[11];
  const float* bt2 = (const float*)d_in[12];
  float* outp = (float*)d_out;

  // workspace layout (floats); total 3,493,888 floats = 13.98 MB
  float* ws  = (float*)d_ws;
  float* qb  = ws;                    // 1,048,576
  float* ktb = qb  + 1048576;         //   262,144
  float* vtb = ktb + 262144;          // 2,097,152
  float* cfr = vtb + 2097152;         //    32,768
  float* cfs = cfr + 32768;           //    32,768
  float* Tb  = cfs + 32768;           //    18,432
  float* cwb = Tb  + 18432;           //     2,048

  // zero atomic-accumulated buffers (q, kt, vt contiguous)
  hipMemsetAsync(qb, 0, (size_t)3407872 * 4, stream);
  hipMemsetAsync(Tb, 0, (size_t)18432 * 4, stream);

  // convs
  conv3x3<<<dim3(16, 1, 32), 256, 0, stream>>>(x1, wq, qb, 64, 64, 256, 64, 4, 32, 2, 4096LL, 1LL);
  conv3x3<<<dim3(4, 1, 128), 256, 0, stream>>>(x2, wk, ktb, 32, 32, 512, 32, 16, 32, 1, 1LL, 32LL);
  conv3x3<<<dim3(4, 8, 16), 256, 0, stream>>>(x2, wv, vtb, 32, 32, 512, 256, 2, 256, 1, 1LL, 256LL);

  // channel branch
  cf_dot<<<dim3(16, 8), 256, 0, stream>>>(x1, wc, cfr);
  cf_softmax<<<dim3(8), 1024, 0, stream>>>(cfr, cfs);
  ykern<<<dim3(16, 8), 256, 0, stream>>>(x1, cfs, Tb);
  chw<<<dim3(8), 256, 0, stream>>>(Tb, wch, wt1, bt1, lng, lnb, wt2, bt2, cwb);

  // fused attention + epilogue
  attn<<<dim3(512, 8), 256, 0, stream>>>(qb, ktb, vtb, x1, cwb, outp);
}

// Round 2
// 1490.198 us; speedup vs baseline: 1.5928x; 1.5928x over previous
//
#include <hip/hip_runtime.h>
#include <stdint.h>

#define LL long long

// ======================================================================
// Generic 3x3 SAME conv (cross-correlation), stride 1.
// tile = 8 rows x 32 cols (256 positions = 256 threads, 1 pos/thread),
// 32 output channels per block held in registers, IC chunked by 4 via LDS.
// Weights read with wave-uniform indices -> s_load.
// IC split across blocks (atomicAdd into pre-zeroed output) for occupancy.
// transposed==0: out[b*OCtot*HW + oc*ocs + pos*ps]  (lane=pixel coalesced)
// transposed==1: ocs==1, ps==OCtot; epilogue transposes acc via per-wave
//                LDS so atomic lanes are oc-consecutive (full-line atomics).
// ======================================================================
__global__ __launch_bounds__(256) void conv3x3(
    const float* __restrict__ in, const float* __restrict__ w, float* __restrict__ out,
    int H, int W, int ICt, int ic_per, int ic_splits, int OCtot, int tiles_x,
    LL ocs, LL ps, int transposed)
{
  // union: staging buffer (4*10*34 = 1360 floats) / transpose scratch (4*64*17)
  __shared__ __align__(16) float smem[4 * 64 * 17];
  float (*xs)[10][34] = (float (*)[10][34])smem;
  float (*tr)[64][17] = (float (*)[64][17])smem;

  const int t    = threadIdx.x;
  const int tile = blockIdx.x;
  const int oc0  = blockIdx.y * 32;
  const int z    = blockIdx.z;
  const int b    = z / ic_splits;
  const int ic0  = (z - b * ic_splits) * ic_per;
  const int HW   = H * W;
  const int ty0  = (tile / tiles_x) * 8;
  const int tx0  = (tile % tiles_x) * 32;
  const int ty   = t >> 5, tx = t & 31;

  const float* inb = in + (LL)b * ICt * HW;

  float acc[32];
#pragma unroll
  for (int i = 0; i < 32; ++i) acc[i] = 0.f;

  for (int ic = ic0; ic < ic0 + ic_per; ic += 4) {
    __syncthreads();
    for (int idx = t; idx < 1360; idx += 256) {
      int icl = idx / 340; int rem = idx - icl * 340;
      int ry  = rem / 34;  int rx  = rem - ry * 34;
      int gy  = ty0 + ry - 1, gx = tx0 + rx - 1;
      float v = 0.f;
      if ((unsigned)gy < (unsigned)H && (unsigned)gx < (unsigned)W)
        v = inb[(LL)(ic + icl) * HW + gy * W + gx];
      xs[icl][ry][rx] = v;
    }
    __syncthreads();
#pragma unroll
    for (int icl = 0; icl < 4; ++icl) {
      float xv[9];
#pragma unroll
      for (int dy = 0; dy < 3; ++dy)
#pragma unroll
        for (int dx = 0; dx < 3; ++dx)
          xv[dy * 3 + dx] = xs[icl][ty + dy][tx + dx];
      const float* wic = w + ((LL)oc0 * ICt + (ic + icl)) * 9;
#pragma unroll
      for (int oc = 0; oc < 32; ++oc) {
        const float* wo = wic + (LL)oc * ICt * 9;  // wave-uniform -> s_load
        float s = acc[oc];
        s = fmaf(xv[0], wo[0], s);
        s = fmaf(xv[1], wo[1], s);
        s = fmaf(xv[2], wo[2], s);
        s = fmaf(xv[3], wo[3], s);
        s = fmaf(xv[4], wo[4], s);
        s = fmaf(xv[5], wo[5], s);
        s = fmaf(xv[6], wo[6], s);
        s = fmaf(xv[7], wo[7], s);
        s = fmaf(xv[8], wo[8], s);
        acc[oc] = s;
      }
    }
  }

  if (!transposed) {
    const LL ob = (LL)b * OCtot * HW + (LL)((ty0 + ty) * W + tx0 + tx) * ps;
#pragma unroll
    for (int oc = 0; oc < 32; ++oc)
      atomicAdd(&out[ob + (LL)(oc0 + oc) * ocs], acc[oc]);
  } else {
    // transpose through per-wave LDS: atomic lanes become oc-consecutive
    const int wv = t >> 6, l = t & 63;
    const LL bbase = (LL)b * OCtot * HW;
#pragma unroll
    for (int pass = 0; pass < 2; ++pass) {
      __syncthreads();
#pragma unroll
      for (int j = 0; j < 16; ++j) tr[wv][l][j] = acc[pass * 16 + j];
      __syncthreads();
#pragma unroll
      for (int i = 0; i < 16; ++i) {
        int pl = wv * 64 + i * 4 + (l >> 4);      // local pixel 0..255
        int oc = (l & 15) + pass * 16;
        int py = pl >> 5, px = pl & 31;
        LL addr = bbase + (LL)((ty0 + py) * W + tx0 + px) * ps + (oc0 + oc);
        atomicAdd(&out[addr], tr[wv][i * 4 + (l >> 4)][l & 15]);
      }
    }
  }
}

// ======================================================================
// cf[b][n] = sum_c x1[b][c][n] * wc[c]
// ======================================================================
__global__ __launch_bounds__(256) void cf_dot(
    const float* __restrict__ x1, const float* __restrict__ wc, float* __restrict__ cf)
{
  const int b = blockIdx.y;
  const int n = blockIdx.x * 256 + threadIdx.x;
  const float* xp = x1 + (LL)b * 256 * 4096 + n;
  float a = 0.f;
#pragma unroll 4
  for (int c = 0; c < 256; ++c)
    a = fmaf(xp[(LL)c * 4096], wc[c], a);
  cf[b * 4096 + n] = a;
}

// ======================================================================
// softmax over 4096 per batch
// ======================================================================
__global__ __launch_bounds__(1024) void cf_softmax(
    const float* __restrict__ cf, float* __restrict__ cfs)
{
  const int b = blockIdx.x, t = threadIdx.x;
  __shared__ float r1[16];
  __shared__ float r2[16];
  float v[4];
#pragma unroll
  for (int j = 0; j < 4; ++j) v[j] = cf[b * 4096 + t + 1024 * j];
  float mx = fmaxf(fmaxf(v[0], v[1]), fmaxf(v[2], v[3]));
#pragma unroll
  for (int k = 1; k <= 32; k <<= 1) mx = fmaxf(mx, __shfl_xor(mx, k));
  const int wv = t >> 6;
  if ((t & 63) == 0) r1[wv] = mx;
  __syncthreads();
  float m2 = r1[0];
#pragma unroll
  for (int i = 1; i < 16; ++i) m2 = fmaxf(m2, r1[i]);
  float e[4]; float s = 0.f;
#pragma unroll
  for (int j = 0; j < 4; ++j) { e[j] = __expf(v[j] - m2); s += e[j]; }
#pragma unroll
  for (int k = 1; k <= 32; k <<= 1) s += __shfl_xor(s, k);
  if ((t & 63) == 0) r2[wv] = s;
  __syncthreads();
  float s2 = 0.f;
#pragma unroll
  for (int i = 0; i < 16; ++i) s2 += r2[i];
  const float inv = 1.f / s2;
#pragma unroll
  for (int j = 0; j < 4; ++j) cfs[b * 4096 + t + 1024 * j] = e[j] * inv;
}

// ======================================================================
// T[b][c][dy*3+dx] = sum_{y,x} x1[b][c][y][x] * cfs[b][y+1-dy][x+1-dx]
// ======================================================================
__global__ __launch_bounds__(256) void ykern(
    const float* __restrict__ x1, const float* __restrict__ cfs, float* __restrict__ T)
{
  __shared__ float cl[6][64];
  const int chunk = blockIdx.x, b = blockIdx.y, t = threadIdx.x;
  for (int idx = t; idx < 384; idx += 256) {
    int lr = idx >> 6, col = idx & 63;
    int gr = chunk * 4 - 1 + lr;
    cl[lr][col] = ((unsigned)gr < 64u) ? cfs[b * 4096 + gr * 64 + col] : 0.f;
  }
  __syncthreads();
  const int c = t;
  float a[9];
#pragma unroll
  for (int k = 0; k < 9; ++k) a[k] = 0.f;
  const float* xp = x1 + ((LL)b * 256 + c) * 4096 + chunk * 256;
  for (int i = 0; i < 256; ++i) {
    float xv = xp[i];
    int yl = i >> 6, col = i & 63;
#pragma unroll
    for (int dy = 0; dy < 3; ++dy) {
      int lr = yl + 2 - dy;
#pragma unroll
      for (int dx = 0; dx < 3; ++dx) {
        int cc = col + 1 - dx;
        float f = ((unsigned)cc < 64u) ? cl[lr][cc] : 0.f;
        a[dy * 3 + dx] = fmaf(xv, f, a[dy * 3 + dx]);
      }
    }
  }
#pragma unroll
  for (int k = 0; k < 9; ++k)
    atomicAdd(&T[((LL)b * 256 + c) * 9 + k], a[k]);
}

// ======================================================================
// pool = wch . T ; t1 = wt1.pool + bt1 ; LN(32) ; relu ; cwp1 = 1 + wt2.t + bt2
// ======================================================================
__global__ __launch_bounds__(256) void chw(
    const float* __restrict__ T, const float* __restrict__ wch,
    const float* __restrict__ wt1, const float* __restrict__ bt1,
    const float* __restrict__ lng, const float* __restrict__ lnb,
    const float* __restrict__ wt2, const float* __restrict__ bt2,
    float* __restrict__ cwp1)
{
  const int b = blockIdx.x, t = threadIdx.x;
  __shared__ __align__(16) float Tl[2304];
  __shared__ float pool[256];
  __shared__ float tt[32];
  for (int idx = t; idx < 2304; idx += 256) Tl[idx] = T[(LL)b * 2304 + idx];
  __syncthreads();
  {
    const float4* wp = (const float4*)(wch + (LL)t * 2304);
    const float4* tp = (const float4*)Tl;
    float a = 0.f;
    for (int i = 0; i < 576; ++i) {
      float4 w4 = wp[i], t4 = tp[i];
      a = fmaf(w4.x, t4.x, a); a = fmaf(w4.y, t4.y, a);
      a = fmaf(w4.z, t4.z, a); a = fmaf(w4.w, t4.w, a);
    }
    pool[t] = a;
  }
  __syncthreads();
  if (t < 64) {
    float tv = 0.f;
    if (t < 32) {
      const float* wp = wt1 + (LL)t * 256;
      for (int c = 0; c < 256; ++c) tv = fmaf(wp[c], pool[c], tv);
      tv += bt1[t];
    }
    float s = tv;
#pragma unroll
    for (int k = 1; k <= 16; k <<= 1) s += __shfl_xor(s, k);
    float mu = s * (1.f / 32.f);
    float d = tv - mu;
    float vs = d * d;
#pragma unroll
    for (int k = 1; k <= 16; k <<= 1) vs += __shfl_xor(vs, k);
    float var = vs * (1.f / 32.f);
    if (t < 32) {
      float nrm = d / sqrtf(var + 1e-5f);
      float y = nrm * lng[t] + lnb[t];
      tt[t] = fmaxf(y, 0.f);
    }
  }
  __syncthreads();
  {
    float s2 = bt2[t];
    const float* wp = wt2 + (LL)t * 32;
#pragma unroll
    for (int i = 0; i < 32; ++i) s2 = fmaf(wp[i], tt[i], s2);
    cwp1[b * 256 + t] = 1.f + s2;
  }
}

// ======================================================================
// Fused attention + epilogue (unchanged from R1; correct at absmax 0.0625)
// ======================================================================
__device__ __forceinline__ unsigned short f2bf(float f) {
  unsigned u = __float_as_uint(f);
  unsigned r = (u + 0x7fffu + ((u >> 16) & 1u)) >> 16;
  return (unsigned short)r;
}

__global__ __launch_bounds__(256) void attn(
    const float* __restrict__ q, const float* __restrict__ kt,
    const float* __restrict__ vt, const float* __restrict__ x1,
    const float* __restrict__ cwp1, float* __restrict__ out)
{
  __shared__ __align__(16) float S[1024][8];
  __shared__ __align__(16) unsigned short P[1024][8];
  __shared__ __align__(16) float qld[32][8];
  __shared__ float red[2][4][8];
  __shared__ float invl[8];

  const int t = threadIdx.x;
  const int b = blockIdx.y;
  const int mb = blockIdx.x * 8;

  {
    int c = t >> 3, m = t & 7;
    qld[c][m] = q[((LL)b * 32 + c) * 4096 + mb + m];
  }
  __syncthreads();

#pragma unroll
  for (int jp = 0; jp < 2; ++jp) {
    const int n0 = t + 512 * jp;
    const int n1 = n0 + 256;
    float K0[32], K1[32];
    const float4* kp0 = (const float4*)(kt + ((LL)b * 1024 + n0) * 32);
    const float4* kp1 = (const float4*)(kt + ((LL)b * 1024 + n1) * 32);
#pragma unroll
    for (int r = 0; r < 8; ++r) {
      float4 a = kp0[r];
      K0[4 * r] = a.x; K0[4 * r + 1] = a.y; K0[4 * r + 2] = a.z; K0[4 * r + 3] = a.w;
      float4 c4 = kp1[r];
      K1[4 * r] = c4.x; K1[4 * r + 1] = c4.y; K1[4 * r + 2] = c4.z; K1[4 * r + 3] = c4.w;
    }
    float a0[8], a1[8];
#pragma unroll
    for (int m = 0; m < 8; ++m) { a0[m] = 0.f; a1[m] = 0.f; }
#pragma unroll
    for (int c = 0; c < 32; ++c) {
      float4 qa = *(const float4*)&qld[c][0];
      float4 qb = *(const float4*)&qld[c][4];
      float qv[8] = {qa.x, qa.y, qa.z, qa.w, qb.x, qb.y, qb.z, qb.w};
      float k0 = K0[c], k1 = K1[c];
#pragma unroll
      for (int m = 0; m < 8; ++m) {
        a0[m] = fmaf(k0, qv[m], a0[m]);
        a1[m] = fmaf(k1, qv[m], a1[m]);
      }
    }
#pragma unroll
    for (int m = 0; m < 8; ++m) { S[n0][m] = a0[m]; S[n1][m] = a1[m]; }
  }
  __syncthreads();

  {
    const int m = t & 7, l = t >> 3;
    float mx = -3.4e38f;
    for (int i = 0; i < 32; ++i) mx = fmaxf(mx, S[l + 32 * i][m]);
    mx = fmaxf(mx, __shfl_xor(mx, 8));
    mx = fmaxf(mx, __shfl_xor(mx, 16));
    mx = fmaxf(mx, __shfl_xor(mx, 32));
    const int wv = t >> 6;
    if ((t & 63) < 8) red[0][wv][m] = mx;
    __syncthreads();
    mx = fmaxf(fmaxf(red[0][0][m], red[0][1][m]), fmaxf(red[0][2][m], red[0][3][m]));
    float sm = 0.f;
    for (int i = 0; i < 32; ++i) {
      int n = l + 32 * i;
      float e = __expf(S[n][m] - mx);
      sm += e;
      P[n][m] = f2bf(e);
    }
    sm += __shfl_xor(sm, 8);
    sm += __shfl_xor(sm, 16);
    sm += __shfl_xor(sm, 32);
    if ((t & 63) < 8) red[1][wv][m] = sm;
    __syncthreads();
    sm = red[1][0][m] + red[1][1][m] + red[1][2][m] + red[1][3][m];
    if (t < 8) invl[t] = 1.f / sm;
  }
  __syncthreads();

  const int ng = t & 7, cb = t >> 3;
  const int c0 = cb * 8;
  float acc[8][8];
#pragma unroll
  for (int cl = 0; cl < 8; ++cl)
#pragma unroll
    for (int m = 0; m < 8; ++m) acc[cl][m] = 0.f;

  const float* vbase = vt + (LL)b * 1024 * 256 + (LL)ng * 256 + c0;
  const unsigned short* Pbase = &P[ng][0];
#pragma unroll 2
  for (int i = 0; i < 128; ++i) {
    const float4* vp = (const float4*)(vbase + (LL)i * 2048);
    float4 v0 = vp[0], v1 = vp[1];
    uint4 pr = *(const uint4*)(Pbase + (size_t)i * 64);
    float p[8];
    p[0] = __uint_as_float(pr.x << 16); p[1] = __uint_as_float(pr.x & 0xffff0000u);
    p[2] = __uint_as_float(pr.y << 16); p[3] = __uint_as_float(pr.y & 0xffff0000u);
    p[4] = __uint_as_float(pr.z << 16); p[5] = __uint_as_float(pr.z & 0xffff0000u);
    p[6] = __uint_as_float(pr.w << 16); p[7] = __uint_as_float(pr.w & 0xffff0000u);
    float vv[8] = {v0.x, v0.y, v0.z, v0.w, v1.x, v1.y, v1.z, v1.w};
#pragma unroll
    for (int cl = 0; cl < 8; ++cl)
#pragma unroll
      for (int m = 0; m < 8; ++m)
        acc[cl][m] = fmaf(vv[cl], p[m], acc[cl][m]);
  }

#pragma unroll
  for (int bm = 4; bm >= 1; bm >>= 1) {
    const bool up = (ng & bm) != 0;
#pragma unroll
    for (int j = 0; j < 8; ++j) {
      if (j >= bm) break;
#pragma unroll
      for (int m = 0; m < 8; ++m) {
        float send = up ? acc[j][m] : acc[j + bm][m];
        float keep = up ? acc[j + bm][m] : acc[j][m];
        float got = __shfl_xor(send, bm);
        acc[j][m] = keep + got;
      }
    }
  }

  {
    const int c = c0 + ng;
    const float cw = cwp1[b * 256 + c];
    const float* x1p = x1 + ((LL)b * 256 + c) * 4096 + mb;
    float* op = out + ((LL)b * 256 + c) * 4096 + mb;
#pragma unroll
    for (int m = 0; m < 8; ++m)
      op[m] = fmaf(acc[0][m], invl[m], x1p[m] * cw);
  }
}

// ======================================================================
// launch
// ======================================================================
extern "C" void kernel_launch(void* const* d_in, const int* in_sizes, int n_in,
                              void* d_out, int out_size, void* d_ws, size_t ws_size,
                              hipStream_t stream) {
  const float* x1  = (const float*)d_in[0];
  const float* x2  = (const float*)d_in[1];
  const float* wq  = (const float*)d_in[2];
  const float* wk  = (const float*)d_in[3];
  const float* wv  = (const float*)d_in[4];
  const float* wc  = (const float*)d_in[5];
  const float* wch = (const float*)d_in[6];
  const float* wt1 = (const float*)d_in[7];
  const float* bt1 = (const float*)d_in[8];
  const float* lng = (const float*)d_in[9];
  const float* lnb = (const float*)d_in[10];
  const float* wt2 = (const float*)d_in[11];
  const float* bt2 = (const float*)d_in[12];
  float* outp = (float*)d_out;

  float* ws  = (float*)d_ws;
  float* qb  = ws;                    // 1,048,576
  float* ktb = qb  + 1048576;         //   262,144
  float* vtb = ktb + 262144;          // 2,097,152
  float* cfr = vtb + 2097152;         //    32,768
  float* cfs = cfr + 32768;           //    32,768
  float* Tb  = cfs + 32768;           //    18,432
  float* cwb = Tb  + 18432;           //     2,048

  hipMemsetAsync(qb, 0, (size_t)3407872 * 4, stream);
  hipMemsetAsync(Tb, 0, (size_t)18432 * 4, stream);

  // convs — ic-split boosted for occupancy (4-8 blocks/CU)
  // q: natural layout, ic_per=32, splits=8 -> 1024 blocks
  conv3x3<<<dim3(16, 1, 64), 256, 0, stream>>>(x1, wq, qb, 64, 64, 256, 32, 8, 32, 2, 4096LL, 1LL, 0);
  // k: transposed, ic_per=16, splits=32 -> 1024 blocks
  conv3x3<<<dim3(4, 1, 256), 256, 0, stream>>>(x2, wk, ktb, 32, 32, 512, 16, 32, 32, 1, 1LL, 32LL, 1);
  // v: transposed, ic_per=64, splits=8 -> 2048 blocks
  conv3x3<<<dim3(4, 8, 64), 256, 0, stream>>>(x2, wv, vtb, 32, 32, 512, 64, 8, 256, 1, 1LL, 256LL, 1);

  // channel branch
  cf_dot<<<dim3(16, 8), 256, 0, stream>>>(x1, wc, cfr);
  cf_softmax<<<dim3(8), 1024, 0, stream>>>(cfr, cfs);
  ykern<<<dim3(16, 8), 256, 0, stream>>>(x1, cfs, Tb);
  chw<<<dim3(8), 256, 0, stream>>>(Tb, wch, wt1, bt1, lng, lnb, wt2, bt2, cwb);

  // fused attention + epilogue
  attn<<<dim3(512, 8), 256, 0, stream>>>(qb, ktb, vtb, x1, cwb, outp);
}

// Round 3
// 1059.653 us; speedup vs baseline: 2.2399x; 1.4063x over previous
//
#include <hip/hip_runtime.h>
#include <stdint.h>

#define LL long long

typedef short short8 __attribute__((ext_vector_type(8)));
typedef float f32x4 __attribute__((ext_vector_type(4)));

__device__ __forceinline__ unsigned short f2bf(float f) {
  unsigned u = __float_as_uint(f);
  unsigned r = (u + 0x7fffu + ((u >> 16) & 1u)) >> 16;
  return (unsigned short)r;
}
__device__ __forceinline__ float bf2f(unsigned short h) {
  return __uint_as_float(((unsigned)h) << 16);
}
// load 8 consecutive fp32, split into hi/lo bf16 fragments (bf16x2 trick)
__device__ __forceinline__ void split8(const float* __restrict__ p, short8& hi, short8& lo) {
  float4 a = ((const float4*)p)[0], b = ((const float4*)p)[1];
  float x[8] = {a.x, a.y, a.z, a.w, b.x, b.y, b.z, b.w};
#pragma unroll
  for (int j = 0; j < 8; ++j) {
    unsigned short h = f2bf(x[j]);
    hi[j] = (short)h;
    lo[j] = (short)f2bf(x[j] - bf2f(h));
  }
}

#define MFMA16(A, B, C) __builtin_amdgcn_mfma_f32_16x16x32_bf16(A, B, C, 0, 0, 0)

// ======================================================================
// Generic 3x3 SAME conv (unchanged from R2; proven).
// transposed==0: out[b*OCtot*HW + oc*ocs + pos*ps]
// transposed==1: ocs==1, ps==OCtot; LDS transpose -> oc-consecutive atomics
// ======================================================================
__global__ __launch_bounds__(256) void conv3x3(
    const float* __restrict__ in, const float* __restrict__ w, float* __restrict__ out,
    int H, int W, int ICt, int ic_per, int ic_splits, int OCtot, int tiles_x,
    LL ocs, LL ps, int transposed)
{
  __shared__ __align__(16) float smem[4 * 64 * 17];
  float (*xs)[10][34] = (float (*)[10][34])smem;
  float (*tr)[64][17] = (float (*)[64][17])smem;

  const int t    = threadIdx.x;
  const int tile = blockIdx.x;
  const int oc0  = blockIdx.y * 32;
  const int z    = blockIdx.z;
  const int b    = z / ic_splits;
  const int ic0  = (z - b * ic_splits) * ic_per;
  const int HW   = H * W;
  const int ty0  = (tile / tiles_x) * 8;
  const int tx0  = (tile % tiles_x) * 32;
  const int ty   = t >> 5, tx = t & 31;

  const float* inb = in + (LL)b * ICt * HW;

  float acc[32];
#pragma unroll
  for (int i = 0; i < 32; ++i) acc[i] = 0.f;

  for (int ic = ic0; ic < ic0 + ic_per; ic += 4) {
    __syncthreads();
    for (int idx = t; idx < 1360; idx += 256) {
      int icl = idx / 340; int rem = idx - icl * 340;
      int ry  = rem / 34;  int rx  = rem - ry * 34;
      int gy  = ty0 + ry - 1, gx = tx0 + rx - 1;
      float v = 0.f;
      if ((unsigned)gy < (unsigned)H && (unsigned)gx < (unsigned)W)
        v = inb[(LL)(ic + icl) * HW + gy * W + gx];
      xs[icl][ry][rx] = v;
    }
    __syncthreads();
#pragma unroll
    for (int icl = 0; icl < 4; ++icl) {
      float xv[9];
#pragma unroll
      for (int dy = 0; dy < 3; ++dy)
#pragma unroll
        for (int dx = 0; dx < 3; ++dx)
          xv[dy * 3 + dx] = xs[icl][ty + dy][tx + dx];
      const float* wic = w + ((LL)oc0 * ICt + (ic + icl)) * 9;
#pragma unroll
      for (int oc = 0; oc < 32; ++oc) {
        const float* wo = wic + (LL)oc * ICt * 9;  // wave-uniform -> s_load
        float s = acc[oc];
        s = fmaf(xv[0], wo[0], s);
        s = fmaf(xv[1], wo[1], s);
        s = fmaf(xv[2], wo[2], s);
        s = fmaf(xv[3], wo[3], s);
        s = fmaf(xv[4], wo[4], s);
        s = fmaf(xv[5], wo[5], s);
        s = fmaf(xv[6], wo[6], s);
        s = fmaf(xv[7], wo[7], s);
        s = fmaf(xv[8], wo[8], s);
        acc[oc] = s;
      }
    }
  }

  if (!transposed) {
    const LL ob = (LL)b * OCtot * HW + (LL)((ty0 + ty) * W + tx0 + tx) * ps;
#pragma unroll
    for (int oc = 0; oc < 32; ++oc)
      atomicAdd(&out[ob + (LL)(oc0 + oc) * ocs], acc[oc]);
  } else {
    const int wv = t >> 6, l = t & 63;
    const LL bbase = (LL)b * OCtot * HW;
#pragma unroll
    for (int pass = 0; pass < 2; ++pass) {
      __syncthreads();
#pragma unroll
      for (int j = 0; j < 16; ++j) tr[wv][l][j] = acc[pass * 16 + j];
      __syncthreads();
#pragma unroll
      for (int i = 0; i < 16; ++i) {
        int pl = wv * 64 + i * 4 + (l >> 4);
        int oc = (l & 15) + pass * 16;
        int py = pl >> 5, px = pl & 31;
        LL addr = bbase + (LL)((ty0 + py) * W + tx0 + px) * ps + (oc0 + oc);
        atomicAdd(&out[addr], tr[wv][i * 4 + (l >> 4)][l & 15]);
      }
    }
  }
}

// ======================================================================
// fp32 -> bf16 elementwise (for V), 8 elems/thread
// ======================================================================
__global__ __launch_bounds__(256) void cvt_bf16(
    const float* __restrict__ in, unsigned short* __restrict__ o)
{
  const int i = (blockIdx.x * 256 + threadIdx.x) * 8;
  float4 a = ((const float4*)(in + i))[0];
  float4 b = ((const float4*)(in + i))[1];
  uint4 r;
  r.x = (unsigned)f2bf(a.x) | ((unsigned)f2bf(a.y) << 16);
  r.y = (unsigned)f2bf(a.z) | ((unsigned)f2bf(a.w) << 16);
  r.z = (unsigned)f2bf(b.x) | ((unsigned)f2bf(b.y) << 16);
  r.w = (unsigned)f2bf(b.z) | ((unsigned)f2bf(b.w) << 16);
  *(uint4*)(o + i) = r;
}

// ======================================================================
// cf[b][n] = sum_c x1[b][c][n] * wc[c]
// ======================================================================
__global__ __launch_bounds__(256) void cf_dot(
    const float* __restrict__ x1, const float* __restrict__ wc, float* __restrict__ cf)
{
  const int b = blockIdx.y;
  const int n = blockIdx.x * 256 + threadIdx.x;
  const float* xp = x1 + (LL)b * 256 * 4096 + n;
  float a = 0.f;
#pragma unroll 4
  for (int c = 0; c < 256; ++c)
    a = fmaf(xp[(LL)c * 4096], wc[c], a);
  cf[b * 4096 + n] = a;
}

// ======================================================================
// softmax over 4096 per batch
// ======================================================================
__global__ __launch_bounds__(1024) void cf_softmax(
    const float* __restrict__ cf, float* __restrict__ cfs)
{
  const int b = blockIdx.x, t = threadIdx.x;
  __shared__ float r1[16];
  __shared__ float r2[16];
  float v[4];
#pragma unroll
  for (int j = 0; j < 4; ++j) v[j] = cf[b * 4096 + t + 1024 * j];
  float mx = fmaxf(fmaxf(v[0], v[1]), fmaxf(v[2], v[3]));
#pragma unroll
  for (int k = 1; k <= 32; k <<= 1) mx = fmaxf(mx, __shfl_xor(mx, k));
  const int wv = t >> 6;
  if ((t & 63) == 0) r1[wv] = mx;
  __syncthreads();
  float m2 = r1[0];
#pragma unroll
  for (int i = 1; i < 16; ++i) m2 = fmaxf(m2, r1[i]);
  float e[4]; float s = 0.f;
#pragma unroll
  for (int j = 0; j < 4; ++j) { e[j] = __expf(v[j] - m2); s += e[j]; }
#pragma unroll
  for (int k = 1; k <= 32; k <<= 1) s += __shfl_xor(s, k);
  if ((t & 63) == 0) r2[wv] = s;
  __syncthreads();
  float s2 = 0.f;
#pragma unroll
  for (int i = 0; i < 16; ++i) s2 += r2[i];
  const float inv = 1.f / s2;
#pragma unroll
  for (int j = 0; j < 4; ++j) cfs[b * 4096 + t + 1024 * j] = e[j] * inv;
}

// ======================================================================
// T[b][c][dy*3+dx] = sum_{y,x} x1[b][c][y][x] * cfs[b][y+1-dy][x+1-dx]
// ======================================================================
__global__ __launch_bounds__(256) void ykern(
    const float* __restrict__ x1, const float* __restrict__ cfs, float* __restrict__ T)
{
  __shared__ float cl[6][64];
  const int chunk = blockIdx.x, b = blockIdx.y, t = threadIdx.x;
  for (int idx = t; idx < 384; idx += 256) {
    int lr = idx >> 6, col = idx & 63;
    int gr = chunk * 4 - 1 + lr;
    cl[lr][col] = ((unsigned)gr < 64u) ? cfs[b * 4096 + gr * 64 + col] : 0.f;
  }
  __syncthreads();
  const int c = t;
  float a[9];
#pragma unroll
  for (int k = 0; k < 9; ++k) a[k] = 0.f;
  const float* xp = x1 + ((LL)b * 256 + c) * 4096 + chunk * 256;
  for (int i = 0; i < 256; ++i) {
    float xv = xp[i];
    int yl = i >> 6, col = i & 63;
#pragma unroll
    for (int dy = 0; dy < 3; ++dy) {
      int lr = yl + 2 - dy;
#pragma unroll
      for (int dx = 0; dx < 3; ++dx) {
        int cc = col + 1 - dx;
        float f = ((unsigned)cc < 64u) ? cl[lr][cc] : 0.f;
        a[dy * 3 + dx] = fmaf(xv, f, a[dy * 3 + dx]);
      }
    }
  }
#pragma unroll
  for (int k = 0; k < 9; ++k)
    atomicAdd(&T[((LL)b * 256 + c) * 9 + k], a[k]);
}

// ======================================================================
// pool = wch . T ; t1 = wt1.pool + bt1 ; LN(32) ; relu ; cwp1 = 1 + wt2.t + bt2
// ======================================================================
__global__ __launch_bounds__(256) void chw(
    const float* __restrict__ T, const float* __restrict__ wch,
    const float* __restrict__ wt1, const float* __restrict__ bt1,
    const float* __restrict__ lng, const float* __restrict__ lnb,
    const float* __restrict__ wt2, const float* __restrict__ bt2,
    float* __restrict__ cwp1)
{
  const int b = blockIdx.x, t = threadIdx.x;
  __shared__ __align__(16) float Tl[2304];
  __shared__ float pool[256];
  __shared__ float tt[32];
  for (int idx = t; idx < 2304; idx += 256) Tl[idx] = T[(LL)b * 2304 + idx];
  __syncthreads();
  {
    const float4* wp = (const float4*)(wch + (LL)t * 2304);
    const float4* tp = (const float4*)Tl;
    float a = 0.f;
    for (int i = 0; i < 576; ++i) {
      float4 w4 = wp[i], t4 = tp[i];
      a = fmaf(w4.x, t4.x, a); a = fmaf(w4.y, t4.y, a);
      a = fmaf(w4.z, t4.z, a); a = fmaf(w4.w, t4.w, a);
    }
    pool[t] = a;
  }
  __syncthreads();
  if (t < 64) {
    float tv = 0.f;
    if (t < 32) {
      const float* wp = wt1 + (LL)t * 256;
      for (int c = 0; c < 256; ++c) tv = fmaf(wp[c], pool[c], tv);
      tv += bt1[t];
    }
    float s = tv;
#pragma unroll
    for (int k = 1; k <= 16; k <<= 1) s += __shfl_xor(s, k);
    float mu = s * (1.f / 32.f);
    float d = tv - mu;
    float vs = d * d;
#pragma unroll
    for (int k = 1; k <= 16; k <<= 1) vs += __shfl_xor(vs, k);
    float var = vs * (1.f / 32.f);
    if (t < 32) {
      float nrm = d / sqrtf(var + 1e-5f);
      float y = nrm * lng[t] + lnb[t];
      tt[t] = fmaxf(y, 0.f);
    }
  }
  __syncthreads();
  {
    float s2 = bt2[t];
    const float* wp = wt2 + (LL)t * 32;
#pragma unroll
    for (int i = 0; i < 32; ++i) s2 = fmaf(wp[i], tt[i], s2);
    cwp1[b * 256 + t] = 1.f + s2;
  }
}

// ======================================================================
// attn_stats: per (b,m) softmax max & inverse-sum over n=1024.
// Logits via MFMA bf16x2 split (same arithmetic as attn_pv -> consistent).
// Block: 64 queries, 4 waves each cover 256 keys (online max/sum in regs).
// Outputs: mxs = max*log2e, invl = 1/sum.
// ======================================================================
__global__ __launch_bounds__(256) void attn_stats(
    const float* __restrict__ qt, const float* __restrict__ kt,
    float* __restrict__ mxs, float* __restrict__ invl)
{
  const int t = threadIdx.x, w = t >> 6, lane = t & 63;
  const int lo4 = lane & 15, hi4 = lane >> 4;
  const int b = blockIdx.y, mc = blockIdx.x * 64;
  const float L2E = 1.4426950408889634f;

  short8 qh[4], ql[4];
#pragma unroll
  for (int mt = 0; mt < 4; ++mt)
    split8(qt + ((LL)(b * 4096 + mc + mt * 16 + lo4)) * 32 + hi4 * 8, qh[mt], ql[mt]);

  float M[4], L[4];
#pragma unroll
  for (int mt = 0; mt < 4; ++mt) { M[mt] = -1e30f; L[mt] = 0.f; }

  for (int ns = 0; ns < 16; ++ns) {
    const int n = w * 256 + ns * 16 + lo4;
    short8 kh, kl;
    split8(kt + ((LL)(b * 1024 + n)) * 32 + hi4 * 8, kh, kl);
#pragma unroll
    for (int mt = 0; mt < 4; ++mt) {
      f32x4 s = {0.f, 0.f, 0.f, 0.f};
      s = MFMA16(kl, qh[mt], s);
      s = MFMA16(kh, ql[mt], s);
      s = MFMA16(kh, qh[mt], s);
      float lm = fmaxf(fmaxf(s[0], s[1]), fmaxf(s[2], s[3]));
      float nM = fmaxf(M[mt], lm);
      float sc = exp2f((M[mt] - nM) * L2E);
      L[mt] = L[mt] * sc + exp2f((s[0] - nM) * L2E) + exp2f((s[1] - nM) * L2E)
                         + exp2f((s[2] - nM) * L2E) + exp2f((s[3] - nM) * L2E);
      M[mt] = nM;
    }
  }
  // combine lanes sharing the same m column (xor 16, 32)
#pragma unroll
  for (int mask = 16; mask <= 32; mask <<= 1) {
#pragma unroll
    for (int mt = 0; mt < 4; ++mt) {
      float oM = __shfl_xor(M[mt], mask), oL = __shfl_xor(L[mt], mask);
      float nM = fmaxf(M[mt], oM);
      L[mt] = L[mt] * exp2f((M[mt] - nM) * L2E) + oL * exp2f((oM - nM) * L2E);
      M[mt] = nM;
    }
  }
  __shared__ float sM[4][64], sL[4][64];
  if (lane < 16) {
#pragma unroll
    for (int mt = 0; mt < 4; ++mt) {
      sM[w][mt * 16 + lane] = M[mt];
      sL[w][mt * 16 + lane] = L[mt];
    }
  }
  __syncthreads();
  if (t < 64) {
    float Mg = sM[0][t], Lg = sL[0][t];
#pragma unroll
    for (int wv = 1; wv < 4; ++wv) {
      float oM = sM[wv][t], oL = sL[wv][t];
      float nM = fmaxf(Mg, oM);
      Lg = Lg * exp2f((Mg - nM) * L2E) + oL * exp2f((oM - nM) * L2E);
      Mg = nM;
    }
    mxs[b * 4096 + mc + t] = Mg * L2E;
    invl[b * 4096 + mc + t] = 1.f / Lg;
  }
}

// ======================================================================
// attn_pv: fused logits + softmax-apply + PV MFMA + epilogue.
// Block: 32 queries (mb), all 1024 keys, all 256 channels. 4 waves.
//   GEMM1 (bf16x2): S[n][m], n-tile=128 (wave n-sub=32), C/D layout regs
//   P = exp2(S*l2e - mxs)*invl -> bf16 -> LDS Pt[m][n] (B-operand layout)
//   GEMM2: acc[c][m] += V[c][n] @ P[n][m], V bf16 direct from global
//   epilogue: out = acc + x1*(1+cw)
// ======================================================================
__global__ __launch_bounds__(256) void attn_pv(
    const float* __restrict__ qt, const float* __restrict__ kt,
    const unsigned short* __restrict__ v16,
    const float* __restrict__ mxs, const float* __restrict__ invl,
    const float* __restrict__ x1, const float* __restrict__ cwp1,
    float* __restrict__ out)
{
  __shared__ __align__(16) unsigned short Pt[32][136];
  const int t = threadIdx.x, w = t >> 6, lane = t & 63;
  const int lo4 = lane & 15, hi4 = lane >> 4;
  const int b = blockIdx.y, mb = blockIdx.x * 32;
  const float L2E = 1.4426950408889634f;

  short8 qh[2], ql[2];
  float mxv[2], ilv[2];
#pragma unroll
  for (int mt = 0; mt < 2; ++mt) {
    const int m = mb + mt * 16 + lo4;
    split8(qt + ((LL)(b * 4096 + m)) * 32 + hi4 * 8, qh[mt], ql[mt]);
    mxv[mt] = mxs[b * 4096 + m];
    ilv[mt] = invl[b * 4096 + m];
  }

  f32x4 acc[4][2];
#pragma unroll
  for (int ct = 0; ct < 4; ++ct)
#pragma unroll
    for (int mt = 0; mt < 2; ++mt) acc[ct][mt] = (f32x4){0.f, 0.f, 0.f, 0.f};

  for (int nt = 0; nt < 8; ++nt) {
    const int n0 = nt * 128;
    // ---- GEMM1: logits for my 32-key slice ----
    f32x4 s[2][2];
    short8 kh[2], kl[2];
#pragma unroll
    for (int ns = 0; ns < 2; ++ns)
      split8(kt + ((LL)(b * 1024 + n0 + w * 32 + ns * 16 + lo4)) * 32 + hi4 * 8,
             kh[ns], kl[ns]);
#pragma unroll
    for (int ns = 0; ns < 2; ++ns)
#pragma unroll
      for (int mt = 0; mt < 2; ++mt) {
        f32x4 z = {0.f, 0.f, 0.f, 0.f};
        z = MFMA16(kl[ns], qh[mt], z);
        z = MFMA16(kh[ns], ql[mt], z);
        z = MFMA16(kh[ns], qh[mt], z);
        s[ns][mt] = z;
      }
    __syncthreads();  // prev GEMM2 done reading Pt
    // ---- softmax-apply -> Pt (bf16, [m][n] = B-operand layout) ----
#pragma unroll
    for (int ns = 0; ns < 2; ++ns)
#pragma unroll
      for (int mt = 0; mt < 2; ++mt) {
        const int m_loc = mt * 16 + lo4;
        const int nl = w * 32 + ns * 16 + hi4 * 4;
#pragma unroll
        for (int rp = 0; rp < 2; ++rp) {
          float p0 = exp2f(fmaf(s[ns][mt][2 * rp],     L2E, -mxv[mt])) * ilv[mt];
          float p1 = exp2f(fmaf(s[ns][mt][2 * rp + 1], L2E, -mxv[mt])) * ilv[mt];
          unsigned u = (unsigned)f2bf(p0) | ((unsigned)f2bf(p1) << 16);
          *(unsigned*)&Pt[m_loc][nl + 2 * rp] = u;
        }
      }
    __syncthreads();  // Pt visible
    // ---- GEMM2: acc += V @ P ----
#pragma unroll
    for (int ks = 0; ks < 4; ++ks) {
      short8 pb[2];
#pragma unroll
      for (int mt = 0; mt < 2; ++mt)
        pb[mt] = *(const short8*)&Pt[mt * 16 + lo4][ks * 32 + hi4 * 8];
#pragma unroll
      for (int ct = 0; ct < 4; ++ct) {
        const short8 va = *(const short8*)(
            v16 + ((LL)(b * 256 + w * 64 + ct * 16 + lo4)) * 1024 + n0 + ks * 32 + hi4 * 8);
#pragma unroll
        for (int mt = 0; mt < 2; ++mt)
          acc[ct][mt] = MFMA16(va, pb[mt], acc[ct][mt]);
      }
    }
  }

  // ---- epilogue: out = acc + x1*(1+cw) ----
#pragma unroll
  for (int ct = 0; ct < 4; ++ct)
#pragma unroll
    for (int mt = 0; mt < 2; ++mt) {
      const int m = mb + mt * 16 + lo4;
#pragma unroll
      for (int r = 0; r < 4; ++r) {
        const int c = w * 64 + ct * 16 + hi4 * 4 + r;
        const float cw = cwp1[b * 256 + c];
        const LL off = ((LL)(b * 256 + c)) * 4096 + m;
        out[off] = acc[ct][mt][r] + x1[off] * cw;
      }
    }
}

// ======================================================================
// launch
// ======================================================================
extern "C" void kernel_launch(void* const* d_in, const int* in_sizes, int n_in,
                              void* d_out, int out_size, void* d_ws, size_t ws_size,
                              hipStream_t stream) {
  const float* x1  = (const float*)d_in[0];
  const float* x2  = (const float*)d_in[1];
  const float* wq  = (const float*)d_in[2];
  const float* wk  = (const float*)d_in[3];
  const float* wv  = (const float*)d_in[4];
  const float* wc  = (const float*)d_in[5];
  const float* wch = (const float*)d_in[6];
  const float* wt1 = (const float*)d_in[7];
  const float* bt1 = (const float*)d_in[8];
  const float* lng = (const float*)d_in[9];
  const float* lnb = (const float*)d_in[10];
  const float* wt2 = (const float*)d_in[11];
  const float* bt2 = (const float*)d_in[12];
  float* outp = (float*)d_out;

  // workspace layout (float offsets); total 4,608,000 floats = 18.4 MB
  float* ws   = (float*)d_ws;
  float* qtf  = ws;                    // [8][4096][32] fp32      1,048,576
  float* ktf  = qtf + 1048576;         // [8][1024][32] fp32        262,144
  float* vf   = ktf + 262144;          // [8][256][1024] fp32     2,097,152
  unsigned short* v16 = (unsigned short*)(vf + 2097152);  // bf16, 1,048,576 slots
  float* mxsb = vf + 2097152 + 1048576;  //    32,768
  float* invb = mxsb + 32768;          //    32,768
  float* cfr  = invb + 32768;          //    32,768
  float* cfs  = cfr + 32768;           //    32,768
  float* Tb   = cfs + 32768;           //    18,432
  float* cwb  = Tb + 18432;            //     2,048

  // zero atomic-accumulated buffers (qtf/ktf/vf contiguous)
  hipMemsetAsync(qtf, 0, (size_t)3407872 * 4, stream);
  hipMemsetAsync(Tb, 0, (size_t)18432 * 4, stream);

  // convs
  // q: transposed [m][32c], ic_per=32, splits=8
  conv3x3<<<dim3(16, 1, 64), 256, 0, stream>>>(x1, wq, qtf, 64, 64, 256, 32, 8, 32, 2, 1LL, 32LL, 1);
  // k: transposed [n][32c], ic_per=16, splits=32
  conv3x3<<<dim3(4, 1, 256), 256, 0, stream>>>(x2, wk, ktf, 32, 32, 512, 16, 32, 32, 1, 1LL, 32LL, 1);
  // v: natural [c][n], ic_per=64, splits=8
  conv3x3<<<dim3(4, 8, 64), 256, 0, stream>>>(x2, wv, vf, 32, 32, 512, 64, 8, 256, 1, 1024LL, 1LL, 0);

  // V -> bf16
  cvt_bf16<<<dim3(1024), 256, 0, stream>>>(vf, v16);

  // channel branch
  cf_dot<<<dim3(16, 8), 256, 0, stream>>>(x1, wc, cfr);
  cf_softmax<<<dim3(8), 1024, 0, stream>>>(cfr, cfs);
  ykern<<<dim3(16, 8), 256, 0, stream>>>(x1, cfs, Tb);
  chw<<<dim3(8), 256, 0, stream>>>(Tb, wch, wt1, bt1, lng, lnb, wt2, bt2, cwb);

  // attention
  attn_stats<<<dim3(64, 8), 256, 0, stream>>>(qtf, ktf, mxsb, invb);
  attn_pv<<<dim3(128, 8), 256, 0, stream>>>(qtf, ktf, v16, mxsb, invb, x1, cwb, outp);
}

// Round 5
// 872.621 us; speedup vs baseline: 2.7200x; 1.2143x over previous
//
#include <hip/hip_runtime.h>
#include <stdint.h>

#define LL long long

typedef short short8 __attribute__((ext_vector_type(8)));
typedef float f32x4 __attribute__((ext_vector_type(4)));

__device__ __forceinline__ unsigned short f2bf(float f) {
  unsigned u = __float_as_uint(f);
  unsigned r = (u + 0x7fffu + ((u >> 16) & 1u)) >> 16;
  return (unsigned short)r;
}
__device__ __forceinline__ float bf2f(unsigned short h) {
  return __uint_as_float(((unsigned)h) << 16);
}
// load 8 consecutive fp32, split into hi/lo bf16 fragments (bf16x2 trick)
__device__ __forceinline__ void split8(const float* __restrict__ p, short8& hi, short8& lo) {
  float4 a = ((const float4*)p)[0], b = ((const float4*)p)[1];
  float x[8] = {a.x, a.y, a.z, a.w, b.x, b.y, b.z, b.w};
#pragma unroll
  for (int j = 0; j < 8; ++j) {
    unsigned short h = f2bf(x[j]);
    hi[j] = (short)h;
    lo[j] = (short)f2bf(x[j] - bf2f(h));
  }
}

#define MFMA16(A, B, C) __builtin_amdgcn_mfma_f32_16x16x32_bf16(A, B, C, 0, 0, 0)

// ======================================================================
// Weight pre-transform: src fp32 [OC][IC][3][3] -> dh/dl bf16 [9][OC][IC]
// (dl == nullptr -> hi only). One thread per element.
// ======================================================================
__global__ __launch_bounds__(256) void wtrans(
    const float* __restrict__ src, unsigned short* __restrict__ dh,
    unsigned short* __restrict__ dl, int OC, int IC)
{
  const int i = blockIdx.x * 256 + threadIdx.x;
  if (i >= OC * IC * 9) return;
  const int off = i % 9;
  const int rest = i / 9;
  const int ic = rest % IC;
  const int oc = rest / IC;
  const float v = src[i];
  const unsigned short h = f2bf(v);
  const int di = (off * OC + oc) * IC + ic;
  dh[di] = h;
  if (dl) dl[di] = f2bf(v - bf2f(h));
}

// ======================================================================
// conv_qk: implicit-GEMM MFMA 3x3 SAME conv, split-precision (bf16x2).
// OC=32. Block: 256 thr, 4 waves: (w&1)->oc half(16), (w>>1)->n half(32).
// n_tile = 64 pixels = rows_out full image rows. K-loop: ic chunks of 32
// staged to LDS [halo_pos][40pad] (hi+lo), x 9 offsets, 3 MFMAs per pair.
// out: fp32 [b][N][32]  (the layout attn_stats/attn_pv read).
// ======================================================================
__global__ __launch_bounds__(256) void conv_qk(
    const float* __restrict__ in, const unsigned short* __restrict__ wt_h,
    const unsigned short* __restrict__ wt_l, float* __restrict__ out,
    int H, int W, int ICt, int shiftW, int rows_out)
{
  __shared__ __align__(16) unsigned short Xh[8400];  // up to 210 pos * 40
  __shared__ __align__(16) unsigned short Xl[8400];

  const int t = threadIdx.x, w = t >> 6, lane = t & 63;
  const int lo4 = lane & 15, hi4 = lane >> 4;
  const int b = blockIdx.z, tile = blockIdx.x;
  const int ocb = w & 1, nhalf = w >> 1;
  const int y0 = tile * rows_out;
  const int Wh = W + 2, hrows = rows_out + 2;
  const int Ntot = H * W;

  f32x4 acc[2];
  acc[0] = (f32x4){0.f, 0.f, 0.f, 0.f};
  acc[1] = (f32x4){0.f, 0.f, 0.f, 0.f};

  for (int ic0 = 0; ic0 < ICt; ic0 += 32) {
    __syncthreads();
    // stage ic-chunk (pairs of ic -> one b32 LDS write each for h and l)
    for (int ic = 0; ic < 32; ic += 2) {
      const float* p0 = in + ((LL)(b * ICt + ic0 + ic)) * H * W;
      const float* p1 = p0 + (LL)H * W;
      for (int hr = w; hr < hrows; hr += 4) {
        const int gy = y0 - 1 + hr;
        const bool yok = (unsigned)gy < (unsigned)H;
        for (int hc = lane; hc < Wh; hc += 64) {
          const int gx = hc - 1;
          const bool ok = yok && ((unsigned)gx < (unsigned)W);
          float v0 = ok ? p0[gy * W + gx] : 0.f;
          float v1 = ok ? p1[gy * W + gx] : 0.f;
          unsigned short h0 = f2bf(v0), h1 = f2bf(v1);
          unsigned short l0 = f2bf(v0 - bf2f(h0)), l1 = f2bf(v1 - bf2f(h1));
          const int sidx = (hr * Wh + hc) * 40 + ic;
          *(unsigned*)&Xh[sidx] = (unsigned)h0 | ((unsigned)h1 << 16);
          *(unsigned*)&Xl[sidx] = (unsigned)l0 | ((unsigned)l1 << 16);
        }
      }
    }
    __syncthreads();
#pragma unroll
    for (int off = 0; off < 9; ++off) {
      const int ky = off / 3, kx = off % 3;
      const LL wi = ((LL)(off * 32 + ocb * 16 + lo4)) * ICt + ic0 + hi4 * 8;
      const short8 Ah = *(const short8*)(wt_h + wi);
      const short8 Al = *(const short8*)(wt_l + wi);
#pragma unroll
      for (int sub = 0; sub < 2; ++sub) {
        const int p = nhalf * 32 + sub * 16 + lo4;
        const int ry = p >> shiftW, rx = p & (W - 1);
        const int pos = (ry + ky) * Wh + rx + kx;
        const short8 Bh = *(const short8*)&Xh[pos * 40 + hi4 * 8];
        const short8 Bl = *(const short8*)&Xl[pos * 40 + hi4 * 8];
        acc[sub] = MFMA16(Ah, Bh, acc[sub]);
        acc[sub] = MFMA16(Ah, Bl, acc[sub]);
        acc[sub] = MFMA16(Al, Bh, acc[sub]);
      }
    }
  }
  // epilogue: out[(b*Ntot + n)*32 + oc], 4 consecutive oc per lane -> float4
#pragma unroll
  for (int sub = 0; sub < 2; ++sub) {
    const int n = tile * 64 + nhalf * 32 + sub * 16 + lo4;
    float* op = out + ((LL)(b * Ntot + n)) * 32 + ocb * 16 + hi4 * 4;
    *(float4*)op = *(float4*)&acc[sub];
  }
}

// ======================================================================
// conv_v: implicit-GEMM MFMA 3x3 SAME conv, single bf16 pass.
// IC=512, OC=256, H=W=32. Block: 4 waves, wave w -> oc w*16..+16 within
// a 64-oc tile; n_tile = 64 px (2 rows). out: bf16 [b][256][1024].
// ======================================================================
__global__ __launch_bounds__(256) void conv_v_mfma(
    const float* __restrict__ in, const unsigned short* __restrict__ wt,
    unsigned short* __restrict__ out)
{
  __shared__ __align__(16) unsigned short Xs[5440];  // 136 pos * 40

  const int t = threadIdx.x, w = t >> 6, lane = t & 63;
  const int lo4 = lane & 15, hi4 = lane >> 4;
  const int b = blockIdx.z, tile = blockIdx.x;
  const int oc0 = blockIdx.y * 64;
  const int y0 = tile * 2;
  const int H = 32, W = 32, ICt = 512, Wh = 34;

  f32x4 acc[4];
#pragma unroll
  for (int s = 0; s < 4; ++s) acc[s] = (f32x4){0.f, 0.f, 0.f, 0.f};

  for (int ic0 = 0; ic0 < ICt; ic0 += 32) {
    __syncthreads();
    for (int ic = 0; ic < 32; ic += 2) {
      const float* p0 = in + ((LL)(b * ICt + ic0 + ic)) * H * W;
      const float* p1 = p0 + (LL)H * W;
      {
        const int hr = w;  // 4 halo rows, 4 waves
        const int gy = y0 - 1 + hr;
        const bool yok = (unsigned)gy < (unsigned)H;
        if (lane < Wh) {
          const int gx = lane - 1;
          const bool ok = yok && ((unsigned)gx < (unsigned)W);
          float v0 = ok ? p0[gy * W + gx] : 0.f;
          float v1 = ok ? p1[gy * W + gx] : 0.f;
          const int sidx = (hr * Wh + lane) * 40 + ic;
          *(unsigned*)&Xs[sidx] = (unsigned)f2bf(v0) | ((unsigned)f2bf(v1) << 16);
        }
      }
    }
    __syncthreads();
#pragma unroll
    for (int off = 0; off < 9; ++off) {
      const int ky = off / 3, kx = off % 3;
      const short8 A = *(const short8*)(
          wt + ((LL)(off * 256 + oc0 + w * 16 + lo4)) * ICt + ic0 + hi4 * 8);
#pragma unroll
      for (int sub = 0; sub < 4; ++sub) {
        const int p = sub * 16 + lo4;
        const int ry = p >> 5, rx = p & 31;
        const int pos = (ry + ky) * Wh + rx + kx;
        const short8 B = *(const short8*)&Xs[pos * 40 + hi4 * 8];
        acc[sub] = MFMA16(A, B, acc[sub]);
      }
    }
  }
  // epilogue: out[b][oc][n] bf16
#pragma unroll
  for (int sub = 0; sub < 4; ++sub) {
    const int n = tile * 64 + sub * 16 + lo4;
#pragma unroll
    for (int r = 0; r < 4; ++r) {
      const int oc = oc0 + w * 16 + hi4 * 4 + r;
      out[((LL)(b * 256 + oc)) * 1024 + n] = f2bf(acc[sub][r]);
    }
  }
}

// ======================================================================
// cf[b][n] = sum_c x1[b][c][n] * wc[c]
// ======================================================================
__global__ __launch_bounds__(256) void cf_dot(
    const float* __restrict__ x1, const float* __restrict__ wc, float* __restrict__ cf)
{
  const int b = blockIdx.y;
  const int n = blockIdx.x * 256 + threadIdx.x;
  const float* xp = x1 + (LL)b * 256 * 4096 + n;
  float a = 0.f;
#pragma unroll 4
  for (int c = 0; c < 256; ++c)
    a = fmaf(xp[(LL)c * 4096], wc[c], a);
  cf[b * 4096 + n] = a;
}

// ======================================================================
// softmax over 4096 per batch
// ======================================================================
__global__ __launch_bounds__(1024) void cf_softmax(
    const float* __restrict__ cf, float* __restrict__ cfs)
{
  const int b = blockIdx.x, t = threadIdx.x;
  __shared__ float r1[16];
  __shared__ float r2[16];
  float v[4];
#pragma unroll
  for (int j = 0; j < 4; ++j) v[j] = cf[b * 4096 + t + 1024 * j];
  float mx = fmaxf(fmaxf(v[0], v[1]), fmaxf(v[2], v[3]));
#pragma unroll
  for (int k = 1; k <= 32; k <<= 1) mx = fmaxf(mx, __shfl_xor(mx, k));
  const int wv = t >> 6;
  if ((t & 63) == 0) r1[wv] = mx;
  __syncthreads();
  float m2 = r1[0];
#pragma unroll
  for (int i = 1; i < 16; ++i) m2 = fmaxf(m2, r1[i]);
  float e[4]; float s = 0.f;
#pragma unroll
  for (int j = 0; j < 4; ++j) { e[j] = __expf(v[j] - m2); s += e[j]; }
#pragma unroll
  for (int k = 1; k <= 32; k <<= 1) s += __shfl_xor(s, k);
  if ((t & 63) == 0) r2[wv] = s;
  __syncthreads();
  float s2 = 0.f;
#pragma unroll
  for (int i = 0; i < 16; ++i) s2 += r2[i];
  const float inv = 1.f / s2;
#pragma unroll
  for (int j = 0; j < 4; ++j) cfs[b * 4096 + t + 1024 * j] = e[j] * inv;
}

// ======================================================================
// T[b][c][dy*3+dx] = sum_{y,x} x1[b][c][y][x] * cfs[b][y+1-dy][x+1-dx]
// ======================================================================
__global__ __launch_bounds__(256) void ykern(
    const float* __restrict__ x1, const float* __restrict__ cfs, float* __restrict__ T)
{
  __shared__ float cl[6][64];
  const int chunk = blockIdx.x, b = blockIdx.y, t = threadIdx.x;
  for (int idx = t; idx < 384; idx += 256) {
    int lr = idx >> 6, col = idx & 63;
    int gr = chunk * 4 - 1 + lr;
    cl[lr][col] = ((unsigned)gr < 64u) ? cfs[b * 4096 + gr * 64 + col] : 0.f;
  }
  __syncthreads();
  const int c = t;
  float a[9];
#pragma unroll
  for (int k = 0; k < 9; ++k) a[k] = 0.f;
  const float* xp = x1 + ((LL)b * 256 + c) * 4096 + chunk * 256;
  for (int i = 0; i < 256; ++i) {
    float xv = xp[i];
    int yl = i >> 6, col = i & 63;
#pragma unroll
    for (int dy = 0; dy < 3; ++dy) {
      int lr = yl + 2 - dy;
#pragma unroll
      for (int dx = 0; dx < 3; ++dx) {
        int cc = col + 1 - dx;
        float f = ((unsigned)cc < 64u) ? cl[lr][cc] : 0.f;
        a[dy * 3 + dx] = fmaf(xv, f, a[dy * 3 + dx]);
      }
    }
  }
#pragma unroll
  for (int k = 0; k < 9; ++k)
    atomicAdd(&T[((LL)b * 256 + c) * 9 + k], a[k]);
}

// ======================================================================
// pool = wch . T ; t1 = wt1.pool + bt1 ; LN(32) ; relu ; cwp1 = 1 + wt2.t + bt2
// ======================================================================
__global__ __launch_bounds__(256) void chw(
    const float* __restrict__ T, const float* __restrict__ wch,
    const float* __restrict__ wt1, const float* __restrict__ bt1,
    const float* __restrict__ lng, const float* __restrict__ lnb,
    const float* __restrict__ wt2, const float* __restrict__ bt2,
    float* __restrict__ cwp1)
{
  const int b = blockIdx.x, t = threadIdx.x;
  __shared__ __align__(16) float Tl[2304];
  __shared__ float pool[256];
  __shared__ float tt[32];
  for (int idx = t; idx < 2304; idx += 256) Tl[idx] = T[(LL)b * 2304 + idx];
  __syncthreads();
  {
    const float4* wp = (const float4*)(wch + (LL)t * 2304);
    const float4* tp = (const float4*)Tl;
    float a = 0.f;
    for (int i = 0; i < 576; ++i) {
      float4 w4 = wp[i], t4 = tp[i];
      a = fmaf(w4.x, t4.x, a); a = fmaf(w4.y, t4.y, a);
      a = fmaf(w4.z, t4.z, a); a = fmaf(w4.w, t4.w, a);
    }
    pool[t] = a;
  }
  __syncthreads();
  if (t < 64) {
    float tv = 0.f;
    if (t < 32) {
      const float* wp = wt1 + (LL)t * 256;
      for (int c = 0; c < 256; ++c) tv = fmaf(wp[c], pool[c], tv);
      tv += bt1[t];
    }
    float s = tv;
#pragma unroll
    for (int k = 1; k <= 16; k <<= 1) s += __shfl_xor(s, k);
    float mu = s * (1.f / 32.f);
    float d = tv - mu;
    float vs = d * d;
#pragma unroll
    for (int k = 1; k <= 16; k <<= 1) vs += __shfl_xor(vs, k);
    float var = vs * (1.f / 32.f);
    if (t < 32) {
      float nrm = d / sqrtf(var + 1e-5f);
      float y = nrm * lng[t] + lnb[t];
      tt[t] = fmaxf(y, 0.f);
    }
  }
  __syncthreads();
  {
    float s2 = bt2[t];
    const float* wp = wt2 + (LL)t * 32;
#pragma unroll
    for (int i = 0; i < 32; ++i) s2 = fmaf(wp[i], tt[i], s2);
    cwp1[b * 256 + t] = 1.f + s2;
  }
}

// ======================================================================
// attn_stats: per (b,m) softmax max & inverse-sum over n=1024 (MFMA bf16x2)
// ======================================================================
__global__ __launch_bounds__(256) void attn_stats(
    const float* __restrict__ qt, const float* __restrict__ kt,
    float* __restrict__ mxs, float* __restrict__ invl)
{
  const int t = threadIdx.x, w = t >> 6, lane = t & 63;
  const int lo4 = lane & 15, hi4 = lane >> 4;
  const int b = blockIdx.y, mc = blockIdx.x * 64;
  const float L2E = 1.4426950408889634f;

  short8 qh[4], ql[4];
#pragma unroll
  for (int mt = 0; mt < 4; ++mt)
    split8(qt + ((LL)(b * 4096 + mc + mt * 16 + lo4)) * 32 + hi4 * 8, qh[mt], ql[mt]);

  float M[4], L[4];
#pragma unroll
  for (int mt = 0; mt < 4; ++mt) { M[mt] = -1e30f; L[mt] = 0.f; }

  for (int ns = 0; ns < 16; ++ns) {
    const int n = w * 256 + ns * 16 + lo4;
    short8 kh, kl;
    split8(kt + ((LL)(b * 1024 + n)) * 32 + hi4 * 8, kh, kl);
#pragma unroll
    for (int mt = 0; mt < 4; ++mt) {
      f32x4 s = {0.f, 0.f, 0.f, 0.f};
      s = MFMA16(kl, qh[mt], s);
      s = MFMA16(kh, ql[mt], s);
      s = MFMA16(kh, qh[mt], s);
      float lm = fmaxf(fmaxf(s[0], s[1]), fmaxf(s[2], s[3]));
      float nM = fmaxf(M[mt], lm);
      float sc = exp2f((M[mt] - nM) * L2E);
      L[mt] = L[mt] * sc + exp2f((s[0] - nM) * L2E) + exp2f((s[1] - nM) * L2E)
                         + exp2f((s[2] - nM) * L2E) + exp2f((s[3] - nM) * L2E);
      M[mt] = nM;
    }
  }
#pragma unroll
  for (int mask = 16; mask <= 32; mask <<= 1) {
#pragma unroll
    for (int mt = 0; mt < 4; ++mt) {
      float oM = __shfl_xor(M[mt], mask), oL = __shfl_xor(L[mt], mask);
      float nM = fmaxf(M[mt], oM);
      L[mt] = L[mt] * exp2f((M[mt] - nM) * L2E) + oL * exp2f((oM - nM) * L2E);
      M[mt] = nM;
    }
  }
  __shared__ float sM[4][64], sL[4][64];
  if (lane < 16) {
#pragma unroll
    for (int mt = 0; mt < 4; ++mt) {
      sM[w][mt * 16 + lane] = M[mt];
      sL[w][mt * 16 + lane] = L[mt];
    }
  }
  __syncthreads();
  if (t < 64) {
    float Mg = sM[0][t], Lg = sL[0][t];
#pragma unroll
    for (int wv = 1; wv < 4; ++wv) {
      float oM = sM[wv][t], oL = sL[wv][t];
      float nM = fmaxf(Mg, oM);
      Lg = Lg * exp2f((Mg - nM) * L2E) + oL * exp2f((oM - nM) * L2E);
      Mg = nM;
    }
    mxs[b * 4096 + mc + t] = Mg * L2E;
    invl[b * 4096 + mc + t] = 1.f / Lg;
  }
}

// ======================================================================
// attn_pv: fused logits + softmax-apply + PV MFMA + epilogue
// ======================================================================
__global__ __launch_bounds__(256) void attn_pv(
    const float* __restrict__ qt, const float* __restrict__ kt,
    const unsigned short* __restrict__ v16,
    const float* __restrict__ mxs, const float* __restrict__ invl,
    const float* __restrict__ x1, const float* __restrict__ cwp1,
    float* __restrict__ out)
{
  __shared__ __align__(16) unsigned short Pt[32][136];
  const int t = threadIdx.x, w = t >> 6, lane = t & 63;
  const int lo4 = lane & 15, hi4 = lane >> 4;
  const int b = blockIdx.y, mb = blockIdx.x * 32;
  const float L2E = 1.4426950408889634f;

  short8 qh[2], ql[2];
  float mxv[2], ilv[2];
#pragma unroll
  for (int mt = 0; mt < 2; ++mt) {
    const int m = mb + mt * 16 + lo4;
    split8(qt + ((LL)(b * 4096 + m)) * 32 + hi4 * 8, qh[mt], ql[mt]);
    mxv[mt] = mxs[b * 4096 + m];
    ilv[mt] = invl[b * 4096 + m];
  }

  f32x4 acc[4][2];
#pragma unroll
  for (int ct = 0; ct < 4; ++ct)
#pragma unroll
    for (int mt = 0; mt < 2; ++mt) acc[ct][mt] = (f32x4){0.f, 0.f, 0.f, 0.f};

  for (int nt = 0; nt < 8; ++nt) {
    const int n0 = nt * 128;
    f32x4 s[2][2];
    short8 kh[2], kl[2];
#pragma unroll
    for (int ns = 0; ns < 2; ++ns)
      split8(kt + ((LL)(b * 1024 + n0 + w * 32 + ns * 16 + lo4)) * 32 + hi4 * 8,
             kh[ns], kl[ns]);
#pragma unroll
    for (int ns = 0; ns < 2; ++ns)
#pragma unroll
      for (int mt = 0; mt < 2; ++mt) {
        f32x4 z = {0.f, 0.f, 0.f, 0.f};
        z = MFMA16(kl[ns], qh[mt], z);
        z = MFMA16(kh[ns], ql[mt], z);
        z = MFMA16(kh[ns], qh[mt], z);
        s[ns][mt] = z;
      }
    __syncthreads();
#pragma unroll
    for (int ns = 0; ns < 2; ++ns)
#pragma unroll
      for (int mt = 0; mt < 2; ++mt) {
        const int m_loc = mt * 16 + lo4;
        const int nl = w * 32 + ns * 16 + hi4 * 4;
#pragma unroll
        for (int rp = 0; rp < 2; ++rp) {
          float p0 = exp2f(fmaf(s[ns][mt][2 * rp],     L2E, -mxv[mt])) * ilv[mt];
          float p1 = exp2f(fmaf(s[ns][mt][2 * rp + 1], L2E, -mxv[mt])) * ilv[mt];
          unsigned u = (unsigned)f2bf(p0) | ((unsigned)f2bf(p1) << 16);
          *(unsigned*)&Pt[m_loc][nl + 2 * rp] = u;
        }
      }
    __syncthreads();
#pragma unroll
    for (int ks = 0; ks < 4; ++ks) {
      short8 pb[2];
#pragma unroll
      for (int mt = 0; mt < 2; ++mt)
        pb[mt] = *(const short8*)&Pt[mt * 16 + lo4][ks * 32 + hi4 * 8];
#pragma unroll
      for (int ct = 0; ct < 4; ++ct) {
        const short8 va = *(const short8*)(
            v16 + ((LL)(b * 256 + w * 64 + ct * 16 + lo4)) * 1024 + n0 + ks * 32 + hi4 * 8);
#pragma unroll
        for (int mt = 0; mt < 2; ++mt)
          acc[ct][mt] = MFMA16(va, pb[mt], acc[ct][mt]);
      }
    }
  }

#pragma unroll
  for (int ct = 0; ct < 4; ++ct)
#pragma unroll
    for (int mt = 0; mt < 2; ++mt) {
      const int m = mb + mt * 16 + lo4;
#pragma unroll
      for (int r = 0; r < 4; ++r) {
        const int c = w * 64 + ct * 16 + hi4 * 4 + r;
        const float cw = cwp1[b * 256 + c];
        const LL off = ((LL)(b * 256 + c)) * 4096 + m;
        out[off] = acc[ct][mt][r] + x1[off] * cw;
      }
    }
}

// ======================================================================
// launch
// ======================================================================
extern "C" void kernel_launch(void* const* d_in, const int* in_sizes, int n_in,
                              void* d_out, int out_size, void* d_ws, size_t ws_size,
                              hipStream_t stream) {
  const float* x1  = (const float*)d_in[0];
  const float* x2  = (const float*)d_in[1];
  const float* wq  = (const float*)d_in[2];
  const float* wk  = (const float*)d_in[3];
  const float* wv  = (const float*)d_in[4];
  const float* wc  = (const float*)d_in[5];
  const float* wch = (const float*)d_in[6];
  const float* wt1 = (const float*)d_in[7];
  const float* bt1 = (const float*)d_in[8];
  const float* lng = (const float*)d_in[9];
  const float* lnb = (const float*)d_in[10];
  const float* wt2 = (const float*)d_in[11];
  const float* bt2 = (const float*)d_in[12];
  float* outp = (float*)d_out;

  // workspace layout — NOTE: all short-typed buffers carved in SHORT units.
  // R4 bug was `wvt = v16 + 1048576` (v16 needs 2,097,152 shorts) -> weights
  // overlapped V's b>=4 half and were stomped mid-kernel. Fixed below.
  // total = 3,321,856 floats = 13.3 MB
  float* ws   = (float*)d_ws;
  float* qtf  = ws;                      // [8][4096][32] fp32   1,048,576 f
  float* ktf  = qtf + 1048576;           // [8][1024][32] fp32     262,144 f
  unsigned short* v16 = (unsigned short*)(ktf + 262144);   // [8][256][1024] = 2,097,152 sh
  unsigned short* wvt = v16 + 2097152;   // [9][256][512] bf16   1,179,648 sh
  unsigned short* wqh = wvt + 1179648;   // [9][32][256] x2         73,728 sh
  unsigned short* wql = wqh + 73728;
  unsigned short* wkh = wql + 73728;     // [9][32][512] x2        147,456 sh
  unsigned short* wkl = wkh + 147456;
  float* mxsb = (float*)(wkl + 147456);  //    32,768 f
  float* invb = mxsb + 32768;            //    32,768 f
  float* cfr  = invb + 32768;            //    32,768 f
  float* cfs  = cfr + 32768;             //    32,768 f
  float* Tb   = cfs + 32768;             //    18,432 f
  float* cwb  = Tb + 18432;              //     2,048 f

  hipMemsetAsync(Tb, 0, (size_t)18432 * 4, stream);

  // weight pre-transforms
  wtrans<<<dim3(4608), 256, 0, stream>>>(wv, wvt, nullptr, 256, 512);
  wtrans<<<dim3(288),  256, 0, stream>>>(wq, wqh, wql, 32, 256);
  wtrans<<<dim3(576),  256, 0, stream>>>(wk, wkh, wkl, 32, 512);

  // MFMA convs
  conv_qk<<<dim3(64, 1, 8), 256, 0, stream>>>(x1, wqh, wql, qtf, 64, 64, 256, 6, 1);
  conv_qk<<<dim3(16, 1, 8), 256, 0, stream>>>(x2, wkh, wkl, ktf, 32, 32, 512, 5, 2);
  conv_v_mfma<<<dim3(16, 4, 8), 256, 0, stream>>>(x2, wvt, v16);

  // channel branch
  cf_dot<<<dim3(16, 8), 256, 0, stream>>>(x1, wc, cfr);
  cf_softmax<<<dim3(8), 1024, 0, stream>>>(cfr, cfs);
  ykern<<<dim3(16, 8), 256, 0, stream>>>(x1, cfs, Tb);
  chw<<<dim3(8), 256, 0, stream>>>(Tb, wch, wt1, bt1, lng, lnb, wt2, bt2, cwb);

  // attention
  attn_stats<<<dim3(64, 8), 256, 0, stream>>>(qtf, ktf, mxsb, invb);
  attn_pv<<<dim3(128, 8), 256, 0, stream>>>(qtf, ktf, v16, mxsb, invb, x1, cwb, outp);
}

// Round 6
// 780.832 us; speedup vs baseline: 3.0398x; 1.1176x over previous
//
#include <hip/hip_runtime.h>
#include <stdint.h>

#define LL long long

typedef short short8 __attribute__((ext_vector_type(8)));
typedef float f32x4 __attribute__((ext_vector_type(4)));

__device__ __forceinline__ unsigned short f2bf(float f) {
  unsigned u = __float_as_uint(f);
  unsigned r = (u + 0x7fffu + ((u >> 16) & 1u)) >> 16;
  return (unsigned short)r;
}
__device__ __forceinline__ float bf2f(unsigned short h) {
  return __uint_as_float(((unsigned)h) << 16);
}
// load 8 consecutive fp32, split into hi/lo bf16 fragments (bf16x2 trick)
__device__ __forceinline__ void split8(const float* __restrict__ p, short8& hi, short8& lo) {
  float4 a = ((const float4*)p)[0], b = ((const float4*)p)[1];
  float x[8] = {a.x, a.y, a.z, a.w, b.x, b.y, b.z, b.w};
#pragma unroll
  for (int j = 0; j < 8; ++j) {
    unsigned short h = f2bf(x[j]);
    hi[j] = (short)h;
    lo[j] = (short)f2bf(x[j] - bf2f(h));
  }
}

#define MFMA16(A, B, C) __builtin_amdgcn_mfma_f32_16x16x32_bf16(A, B, C, 0, 0, 0)

// ======================================================================
// Weight pre-transform: src fp32 [OC][IC][3][3] -> bf16 [9][IC/32][OC][32]
// (A-fragment loads become 1KB-contiguous). dl==nullptr -> hi only.
// ======================================================================
__global__ __launch_bounds__(256) void wtrans2(
    const float* __restrict__ src, unsigned short* __restrict__ dh,
    unsigned short* __restrict__ dl, int OC, int IC)
{
  const int i = blockIdx.x * 256 + threadIdx.x;
  if (i >= OC * IC * 9) return;
  const int off = i % 9;
  const int rest = i / 9;
  const int ic = rest % IC;
  const int oc = rest / IC;
  const float v = src[i];
  const unsigned short h = f2bf(v);
  const LL di = (((LL)off * (IC >> 5) + (ic >> 5)) * OC + oc) * 32 + (ic & 31);
  dh[di] = h;
  if (dl) dl[di] = f2bf(v - bf2f(h));
}

// ======================================================================
// transp: src fp32 [B][C][N] -> dh/dl bf16 [B][N][C]   (64x64 LDS tile)
// phase1 lanes over n (coalesced read), phase2 lanes over c (coalesced write)
// LDS row stride 66 shorts = 33 dwords (odd) -> conflict-free.
// ======================================================================
__global__ __launch_bounds__(256) void transp(
    const float* __restrict__ src, unsigned short* __restrict__ dh,
    unsigned short* __restrict__ dl, int C, int N)
{
  __shared__ unsigned short sh[64 * 66];
  __shared__ unsigned short sl[64 * 66];
  const int t = threadIdx.x;
  const int b = blockIdx.z;
  const int n0 = blockIdx.x * 64, c0 = blockIdx.y * 64;
  {
    const int nl = t & 63, cl0 = t >> 6;
#pragma unroll
    for (int i = 0; i < 16; ++i) {
      const int cl = cl0 + 4 * i;
      const float v = src[((LL)b * C + c0 + cl) * N + n0 + nl];
      const unsigned short h = f2bf(v);
      sh[nl * 66 + cl] = h;
      sl[nl * 66 + cl] = f2bf(v - bf2f(h));
    }
  }
  __syncthreads();
  {
    const int cl = t & 63, nr0 = t >> 6;
#pragma unroll
    for (int j = 0; j < 16; ++j) {
      const int nr = nr0 + 4 * j;
      const LL di = ((LL)b * N + n0 + nr) * C + c0 + cl;
      dh[di] = sh[nr * 66 + cl];
      if (dl) dl[di] = sl[nr * 66 + cl];
    }
  }
}

// ======================================================================
// conv_qk_d: LDS-free direct-load implicit-GEMM 3x3 conv, bf16x2 split.
// wave = 16 px x 32 oc; K split over blockIdx.y (atomicAdd fp32 partials).
// x in [b][n][C] bf16 hi/lo; w in [9][C/32][32][32] hi/lo.
// out fp32 [b][N][32] (pre-zeroed).
// ======================================================================
__global__ __launch_bounds__(256) void conv_qk_d(
    const unsigned short* __restrict__ xh, const unsigned short* __restrict__ xl,
    const unsigned short* __restrict__ wh, const unsigned short* __restrict__ wl,
    float* __restrict__ out, int logW, int H, int C, int chunks_per)
{
  const int t = threadIdx.x, w = t >> 6, lane = t & 63;
  const int lo4 = lane & 15, hi4 = lane >> 4;
  const int b = blockIdx.z;
  const int W = 1 << logW;
  const int N = H * W;
  const int px0 = (blockIdx.x * 4 + w) * 16;
  const int row = px0 >> logW;                 // wave-uniform (16 px in-row)
  const int rx = (px0 & (W - 1)) + lo4;        // lane x
  const int nch = C >> 5;
  const int ch0 = blockIdx.y * chunks_per;
  const short8 zero8 = {0, 0, 0, 0, 0, 0, 0, 0};

  f32x4 acc[2];
  acc[0] = (f32x4){0.f, 0.f, 0.f, 0.f};
  acc[1] = (f32x4){0.f, 0.f, 0.f, 0.f};

  for (int ch = ch0; ch < ch0 + chunks_per; ++ch) {
    const LL xbase = (LL)b * N * C + (LL)ch * 32 + hi4 * 8;
#pragma unroll
    for (int ky = 0; ky < 3; ++ky) {
      const int gy = row + ky - 1;
      if ((unsigned)gy >= (unsigned)H) continue;  // wave-uniform skip
#pragma unroll
      for (int kx = 0; kx < 3; ++kx) {
        const int gx = rx + kx - 1;
        const bool ok = (unsigned)gx < (unsigned)W;
        const LL xoff = xbase + (LL)(gy * W + gx) * C;
        const short8 Bh = ok ? *(const short8*)(xh + xoff) : zero8;
        const short8 Bl = ok ? *(const short8*)(xl + xoff) : zero8;
        const int off = ky * 3 + kx;
#pragma unroll
        for (int ot = 0; ot < 2; ++ot) {
          const LL wi = ((LL)(off * nch + ch) * 32 + ot * 16 + lo4) * 32 + hi4 * 8;
          const short8 Ah = *(const short8*)(wh + wi);
          const short8 Al = *(const short8*)(wl + wi);
          acc[ot] = MFMA16(Ah, Bh, acc[ot]);
          acc[ot] = MFMA16(Ah, Bl, acc[ot]);
          acc[ot] = MFMA16(Al, Bh, acc[ot]);
        }
      }
    }
  }
  const LL ob = ((LL)b * N + px0 + lo4) * 32 + hi4 * 4;
#pragma unroll
  for (int ot = 0; ot < 2; ++ot)
#pragma unroll
    for (int r = 0; r < 4; ++r)
      atomicAdd(&out[ob + ot * 16 + r], acc[ot][r]);
}

// ======================================================================
// conv_v_d: LDS-free direct-load conv, single bf16 pass.
// H=W=32, C=512, OC=256. wave = 16 px x 16 oc (blockIdx.y*4+w).
// out bf16 [b][256][1024].
// ======================================================================
__global__ __launch_bounds__(256) void conv_v_d(
    const unsigned short* __restrict__ xh, const unsigned short* __restrict__ wt,
    unsigned short* __restrict__ out)
{
  const int t = threadIdx.x, w = t >> 6, lane = t & 63;
  const int lo4 = lane & 15, hi4 = lane >> 4;
  const int b = blockIdx.z;
  const int px0 = blockIdx.x * 16;
  const int ot = blockIdx.y * 4 + w;           // oc-tile 0..15
  const int row = px0 >> 5;
  const int rx = (px0 & 31) + lo4;
  const short8 zero8 = {0, 0, 0, 0, 0, 0, 0, 0};

  f32x4 acc = (f32x4){0.f, 0.f, 0.f, 0.f};

  for (int ch = 0; ch < 16; ++ch) {
    const LL xbase = (LL)b * 1024 * 512 + ch * 32 + hi4 * 8;
#pragma unroll
    for (int ky = 0; ky < 3; ++ky) {
      const int gy = row + ky - 1;
      if ((unsigned)gy >= 32u) continue;
#pragma unroll
      for (int kx = 0; kx < 3; ++kx) {
        const int gx = rx + kx - 1;
        const bool ok = (unsigned)gx < 32u;
        const short8 B = ok ? *(const short8*)(xh + xbase + (LL)(gy * 32 + gx) * 512)
                            : zero8;
        const int off = ky * 3 + kx;
        const short8 A = *(const short8*)(
            wt + ((LL)(off * 16 + ch) * 256 + ot * 16 + lo4) * 32 + hi4 * 8);
        acc = MFMA16(A, B, acc);
      }
    }
  }
#pragma unroll
  for (int r = 0; r < 4; ++r) {
    const int oc = ot * 16 + hi4 * 4 + r;
    out[((LL)b * 256 + oc) * 1024 + px0 + lo4] = f2bf(acc[r]);
  }
}

// ======================================================================
// cf[b][n] = sum_c x1[b][c][n] * wc[c]
// ======================================================================
__global__ __launch_bounds__(256) void cf_dot(
    const float* __restrict__ x1, const float* __restrict__ wc, float* __restrict__ cf)
{
  const int b = blockIdx.y;
  const int n = blockIdx.x * 256 + threadIdx.x;
  const float* xp = x1 + (LL)b * 256 * 4096 + n;
  float a = 0.f;
#pragma unroll 4
  for (int c = 0; c < 256; ++c)
    a = fmaf(xp[(LL)c * 4096], wc[c], a);
  cf[b * 4096 + n] = a;
}

// ======================================================================
// softmax over 4096 per batch
// ======================================================================
__global__ __launch_bounds__(1024) void cf_softmax(
    const float* __restrict__ cf, float* __restrict__ cfs)
{
  const int b = blockIdx.x, t = threadIdx.x;
  __shared__ float r1[16];
  __shared__ float r2[16];
  float v[4];
#pragma unroll
  for (int j = 0; j < 4; ++j) v[j] = cf[b * 4096 + t + 1024 * j];
  float mx = fmaxf(fmaxf(v[0], v[1]), fmaxf(v[2], v[3]));
#pragma unroll
  for (int k = 1; k <= 32; k <<= 1) mx = fmaxf(mx, __shfl_xor(mx, k));
  const int wv = t >> 6;
  if ((t & 63) == 0) r1[wv] = mx;
  __syncthreads();
  float m2 = r1[0];
#pragma unroll
  for (int i = 1; i < 16; ++i) m2 = fmaxf(m2, r1[i]);
  float e[4]; float s = 0.f;
#pragma unroll
  for (int j = 0; j < 4; ++j) { e[j] = __expf(v[j] - m2); s += e[j]; }
#pragma unroll
  for (int k = 1; k <= 32; k <<= 1) s += __shfl_xor(s, k);
  if ((t & 63) == 0) r2[wv] = s;
  __syncthreads();
  float s2 = 0.f;
#pragma unroll
  for (int i = 0; i < 16; ++i) s2 += r2[i];
  const float inv = 1.f / s2;
#pragma unroll
  for (int j = 0; j < 4; ++j) cfs[b * 4096 + t + 1024 * j] = e[j] * inv;
}

// ======================================================================
// T[b][c][dy*3+dx] = sum_{y,x} x1[b][c][y][x] * cfs[b][y+1-dy][x+1-dx]
// ======================================================================
__global__ __launch_bounds__(256) void ykern(
    const float* __restrict__ x1, const float* __restrict__ cfs, float* __restrict__ T)
{
  __shared__ float cl[6][64];
  const int chunk = blockIdx.x, b = blockIdx.y, t = threadIdx.x;
  for (int idx = t; idx < 384; idx += 256) {
    int lr = idx >> 6, col = idx & 63;
    int gr = chunk * 4 - 1 + lr;
    cl[lr][col] = ((unsigned)gr < 64u) ? cfs[b * 4096 + gr * 64 + col] : 0.f;
  }
  __syncthreads();
  const int c = t;
  float a[9];
#pragma unroll
  for (int k = 0; k < 9; ++k) a[k] = 0.f;
  const float* xp = x1 + ((LL)b * 256 + c) * 4096 + chunk * 256;
  for (int i = 0; i < 256; ++i) {
    float xv = xp[i];
    int yl = i >> 6, col = i & 63;
#pragma unroll
    for (int dy = 0; dy < 3; ++dy) {
      int lr = yl + 2 - dy;
#pragma unroll
      for (int dx = 0; dx < 3; ++dx) {
        int cc = col + 1 - dx;
        float f = ((unsigned)cc < 64u) ? cl[lr][cc] : 0.f;
        a[dy * 3 + dx] = fmaf(xv, f, a[dy * 3 + dx]);
      }
    }
  }
#pragma unroll
  for (int k = 0; k < 9; ++k)
    atomicAdd(&T[((LL)b * 256 + c) * 9 + k], a[k]);
}

// ======================================================================
// pool = wch . T ; t1 = wt1.pool + bt1 ; LN(32) ; relu ; cwp1 = 1 + wt2.t + bt2
// ======================================================================
__global__ __launch_bounds__(256) void chw(
    const float* __restrict__ T, const float* __restrict__ wch,
    const float* __restrict__ wt1, const float* __restrict__ bt1,
    const float* __restrict__ lng, const float* __restrict__ lnb,
    const float* __restrict__ wt2, const float* __restrict__ bt2,
    float* __restrict__ cwp1)
{
  const int b = blockIdx.x, t = threadIdx.x;
  __shared__ __align__(16) float Tl[2304];
  __shared__ float pool[256];
  __shared__ float tt[32];
  for (int idx = t; idx < 2304; idx += 256) Tl[idx] = T[(LL)b * 2304 + idx];
  __syncthreads();
  {
    const float4* wp = (const float4*)(wch + (LL)t * 2304);
    const float4* tp = (const float4*)Tl;
    float a = 0.f;
    for (int i = 0; i < 576; ++i) {
      float4 w4 = wp[i], t4 = tp[i];
      a = fmaf(w4.x, t4.x, a); a = fmaf(w4.y, t4.y, a);
      a = fmaf(w4.z, t4.z, a); a = fmaf(w4.w, t4.w, a);
    }
    pool[t] = a;
  }
  __syncthreads();
  if (t < 64) {
    float tv = 0.f;
    if (t < 32) {
      const float* wp = wt1 + (LL)t * 256;
      for (int c = 0; c < 256; ++c) tv = fmaf(wp[c], pool[c], tv);
      tv += bt1[t];
    }
    float s = tv;
#pragma unroll
    for (int k = 1; k <= 16; k <<= 1) s += __shfl_xor(s, k);
    float mu = s * (1.f / 32.f);
    float d = tv - mu;
    float vs = d * d;
#pragma unroll
    for (int k = 1; k <= 16; k <<= 1) vs += __shfl_xor(vs, k);
    float var = vs * (1.f / 32.f);
    if (t < 32) {
      float nrm = d / sqrtf(var + 1e-5f);
      float y = nrm * lng[t] + lnb[t];
      tt[t] = fmaxf(y, 0.f);
    }
  }
  __syncthreads();
  {
    float s2 = bt2[t];
    const float* wp = wt2 + (LL)t * 32;
#pragma unroll
    for (int i = 0; i < 32; ++i) s2 = fmaf(wp[i], tt[i], s2);
    cwp1[b * 256 + t] = 1.f + s2;
  }
}

// ======================================================================
// attn_stats: per (b,m) softmax max & inverse-sum over n=1024 (MFMA bf16x2)
// ======================================================================
__global__ __launch_bounds__(256) void attn_stats(
    const float* __restrict__ qt, const float* __restrict__ kt,
    float* __restrict__ mxs, float* __restrict__ invl)
{
  const int t = threadIdx.x, w = t >> 6, lane = t & 63;
  const int lo4 = lane & 15, hi4 = lane >> 4;
  const int b = blockIdx.y, mc = blockIdx.x * 64;
  const float L2E = 1.4426950408889634f;

  short8 qh[4], ql[4];
#pragma unroll
  for (int mt = 0; mt < 4; ++mt)
    split8(qt + ((LL)(b * 4096 + mc + mt * 16 + lo4)) * 32 + hi4 * 8, qh[mt], ql[mt]);

  float M[4], L[4];
#pragma unroll
  for (int mt = 0; mt < 4; ++mt) { M[mt] = -1e30f; L[mt] = 0.f; }

  for (int ns = 0; ns < 16; ++ns) {
    const int n = w * 256 + ns * 16 + lo4;
    short8 kh, kl;
    split8(kt + ((LL)(b * 1024 + n)) * 32 + hi4 * 8, kh, kl);
#pragma unroll
    for (int mt = 0; mt < 4; ++mt) {
      f32x4 s = {0.f, 0.f, 0.f, 0.f};
      s = MFMA16(kl, qh[mt], s);
      s = MFMA16(kh, ql[mt], s);
      s = MFMA16(kh, qh[mt], s);
      float lm = fmaxf(fmaxf(s[0], s[1]), fmaxf(s[2], s[3]));
      float nM = fmaxf(M[mt], lm);
      float sc = exp2f((M[mt] - nM) * L2E);
      L[mt] = L[mt] * sc + exp2f((s[0] - nM) * L2E) + exp2f((s[1] - nM) * L2E)
                         + exp2f((s[2] - nM) * L2E) + exp2f((s[3] - nM) * L2E);
      M[mt] = nM;
    }
  }
#pragma unroll
  for (int mask = 16; mask <= 32; mask <<= 1) {
#pragma unroll
    for (int mt = 0; mt < 4; ++mt) {
      float oM = __shfl_xor(M[mt], mask), oL = __shfl_xor(L[mt], mask);
      float nM = fmaxf(M[mt], oM);
      L[mt] = L[mt] * exp2f((M[mt] - nM) * L2E) + oL * exp2f((oM - nM) * L2E);
      M[mt] = nM;
    }
  }
  __shared__ float sM[4][64], sL[4][64];
  if (lane < 16) {
#pragma unroll
    for (int mt = 0; mt < 4; ++mt) {
      sM[w][mt * 16 + lane] = M[mt];
      sL[w][mt * 16 + lane] = L[mt];
    }
  }
  __syncthreads();
  if (t < 64) {
    float Mg = sM[0][t], Lg = sL[0][t];
#pragma unroll
    for (int wv = 1; wv < 4; ++wv) {
      float oM = sM[wv][t], oL = sL[wv][t];
      float nM = fmaxf(Mg, oM);
      Lg = Lg * exp2f((Mg - nM) * L2E) + oL * exp2f((oM - nM) * L2E);
      Mg = nM;
    }
    mxs[b * 4096 + mc + t] = Mg * L2E;
    invl[b * 4096 + mc + t] = 1.f / Lg;
  }
}

// ======================================================================
// attn_pv: fused logits + softmax-apply + PV MFMA + epilogue
// ======================================================================
__global__ __launch_bounds__(256) void attn_pv(
    const float* __restrict__ qt, const float* __restrict__ kt,
    const unsigned short* __restrict__ v16,
    const float* __restrict__ mxs, const float* __restrict__ invl,
    const float* __restrict__ x1, const float* __restrict__ cwp1,
    float* __restrict__ out)
{
  __shared__ __align__(16) unsigned short Pt[32][136];
  const int t = threadIdx.x, w = t >> 6, lane = t & 63;
  const int lo4 = lane & 15, hi4 = lane >> 4;
  const int b = blockIdx.y, mb = blockIdx.x * 32;
  const float L2E = 1.4426950408889634f;

  short8 qh[2], ql[2];
  float mxv[2], ilv[2];
#pragma unroll
  for (int mt = 0; mt < 2; ++mt) {
    const int m = mb + mt * 16 + lo4;
    split8(qt + ((LL)(b * 4096 + m)) * 32 + hi4 * 8, qh[mt], ql[mt]);
    mxv[mt] = mxs[b * 4096 + m];
    ilv[mt] = invl[b * 4096 + m];
  }

  f32x4 acc[4][2];
#pragma unroll
  for (int ct = 0; ct < 4; ++ct)
#pragma unroll
    for (int mt = 0; mt < 2; ++mt) acc[ct][mt] = (f32x4){0.f, 0.f, 0.f, 0.f};

  for (int nt = 0; nt < 8; ++nt) {
    const int n0 = nt * 128;
    f32x4 s[2][2];
    short8 kh[2], kl[2];
#pragma unroll
    for (int ns = 0; ns < 2; ++ns)
      split8(kt + ((LL)(b * 1024 + n0 + w * 32 + ns * 16 + lo4)) * 32 + hi4 * 8,
             kh[ns], kl[ns]);
#pragma unroll
    for (int ns = 0; ns < 2; ++ns)
#pragma unroll
      for (int mt = 0; mt < 2; ++mt) {
        f32x4 z = {0.f, 0.f, 0.f, 0.f};
        z = MFMA16(kl[ns], qh[mt], z);
        z = MFMA16(kh[ns], ql[mt], z);
        z = MFMA16(kh[ns], qh[mt], z);
        s[ns][mt] = z;
      }
    __syncthreads();
#pragma unroll
    for (int ns = 0; ns < 2; ++ns)
#pragma unroll
      for (int mt = 0; mt < 2; ++mt) {
        const int m_loc = mt * 16 + lo4;
        const int nl = w * 32 + ns * 16 + hi4 * 4;
#pragma unroll
        for (int rp = 0; rp < 2; ++rp) {
          float p0 = exp2f(fmaf(s[ns][mt][2 * rp],     L2E, -mxv[mt])) * ilv[mt];
          float p1 = exp2f(fmaf(s[ns][mt][2 * rp + 1], L2E, -mxv[mt])) * ilv[mt];
          unsigned u = (unsigned)f2bf(p0) | ((unsigned)f2bf(p1) << 16);
          *(unsigned*)&Pt[m_loc][nl + 2 * rp] = u;
        }
      }
    __syncthreads();
#pragma unroll
    for (int ks = 0; ks < 4; ++ks) {
      short8 pb[2];
#pragma unroll
      for (int mt = 0; mt < 2; ++mt)
        pb[mt] = *(const short8*)&Pt[mt * 16 + lo4][ks * 32 + hi4 * 8];
#pragma unroll
      for (int ct = 0; ct < 4; ++ct) {
        const short8 va = *(const short8*)(
            v16 + ((LL)(b * 256 + w * 64 + ct * 16 + lo4)) * 1024 + n0 + ks * 32 + hi4 * 8);
#pragma unroll
        for (int mt = 0; mt < 2; ++mt)
          acc[ct][mt] = MFMA16(va, pb[mt], acc[ct][mt]);
      }
    }
  }

#pragma unroll
  for (int ct = 0; ct < 4; ++ct)
#pragma unroll
    for (int mt = 0; mt < 2; ++mt) {
      const int m = mb + mt * 16 + lo4;
#pragma unroll
      for (int r = 0; r < 4; ++r) {
        const int c = w * 64 + ct * 16 + hi4 * 4 + r;
        const float cw = cwp1[b * 256 + c];
        const LL off = ((LL)(b * 256 + c)) * 4096 + m;
        out[off] = acc[ct][mt][r] + x1[off] * cw;
      }
    }
}

// ======================================================================
// launch
// ======================================================================
extern "C" void kernel_launch(void* const* d_in, const int* in_sizes, int n_in,
                              void* d_out, int out_size, void* d_ws, size_t ws_size,
                              hipStream_t stream) {
  const float* x1  = (const float*)d_in[0];
  const float* x2  = (const float*)d_in[1];
  const float* wq  = (const float*)d_in[2];
  const float* wk  = (const float*)d_in[3];
  const float* wv  = (const float*)d_in[4];
  const float* wc  = (const float*)d_in[5];
  const float* wch = (const float*)d_in[6];
  const float* wt1 = (const float*)d_in[7];
  const float* bt1 = (const float*)d_in[8];
  const float* lng = (const float*)d_in[9];
  const float* lnb = (const float*)d_in[10];
  const float* wt2 = (const float*)d_in[11];
  const float* bt2 = (const float*)d_in[12];
  float* outp = (float*)d_out;

  // ---- workspace (carve floats first, then shorts; ~63.6 MB total) ----
  float* ws   = (float*)d_ws;
  float* qtf  = ws;                      // [8][4096][32] fp32   1,048,576 f
  float* ktf  = qtf + 1048576;           // [8][1024][32] fp32     262,144 f
  float* mxsb = ktf + 262144;            //    32,768 f
  float* invb = mxsb + 32768;            //    32,768 f
  float* cfr  = invb + 32768;            //    32,768 f
  float* cfs  = cfr + 32768;             //    32,768 f
  float* Tb   = cfs + 32768;             //    18,432 f
  float* cwb  = Tb + 18432;              //     2,048 f
  unsigned short* sbase = (unsigned short*)(cwb + 2048);
  unsigned short* v16  = sbase;          // [8][256][1024]       2,097,152 sh
  unsigned short* x1th = v16  + 2097152; // [8][4096][256]       8,388,608 sh
  unsigned short* x1tl = x1th + 8388608;
  unsigned short* x2th = x1tl + 8388608; // [8][1024][512]       4,194,304 sh
  unsigned short* x2tl = x2th + 4194304;
  unsigned short* wvt  = x2tl + 4194304; // [9][16][256][32]     1,179,648 sh
  unsigned short* wqh  = wvt  + 1179648; // [9][8][32][32]          73,728 sh
  unsigned short* wql  = wqh  + 73728;
  unsigned short* wkh  = wql  + 73728;   // [9][16][32][32]        147,456 sh
  unsigned short* wkl  = wkh  + 147456;

  // zero the atomic-accumulated buffers (qtf+ktf contiguous) and Tb
  hipMemsetAsync(qtf, 0, (size_t)(1048576 + 262144) * 4, stream);
  hipMemsetAsync(Tb, 0, (size_t)18432 * 4, stream);

  // weight pre-transforms ([9][IC/32][OC][32])
  wtrans2<<<dim3(4608), 256, 0, stream>>>(wv, wvt, nullptr, 256, 512);
  wtrans2<<<dim3(288),  256, 0, stream>>>(wq, wqh, wql, 32, 256);
  wtrans2<<<dim3(576),  256, 0, stream>>>(wk, wkh, wkl, 32, 512);

  // input transposes: [b][c][n] fp32 -> [b][n][c] bf16 hi/lo
  transp<<<dim3(64, 4, 8), 256, 0, stream>>>(x1, x1th, x1tl, 256, 4096);
  transp<<<dim3(16, 8, 8), 256, 0, stream>>>(x2, x2th, x2tl, 512, 1024);

  // direct-load MFMA convs
  conv_qk_d<<<dim3(64, 4, 8), 256, 0, stream>>>(x1th, x1tl, wqh, wql, qtf, 6, 64, 256, 2);
  conv_qk_d<<<dim3(16, 8, 8), 256, 0, stream>>>(x2th, x2tl, wkh, wkl, ktf, 5, 32, 512, 2);
  conv_v_d<<<dim3(64, 4, 8), 256, 0, stream>>>(x2th, wvt, v16);

  // channel branch
  cf_dot<<<dim3(16, 8), 256, 0, stream>>>(x1, wc, cfr);
  cf_softmax<<<dim3(8), 1024, 0, stream>>>(cfr, cfs);
  ykern<<<dim3(16, 8), 256, 0, stream>>>(x1, cfs, Tb);
  chw<<<dim3(8), 256, 0, stream>>>(Tb, wch, wt1, bt1, lng, lnb, wt2, bt2, cwb);

  // attention
  attn_stats<<<dim3(64, 8), 256, 0, stream>>>(qtf, ktf, mxsb, invb);
  attn_pv<<<dim3(128, 8), 256, 0, stream>>>(qtf, ktf, v16, mxsb, invb, x1, cwb, outp);
}